// Round 9
// baseline (528.680 us; speedup 1.0000x reference)
//
#include <hip/hip_runtime.h>
#include <math.h>

// TriangleAttention: B=1, I=J=384, C=128, H=4, D=32, fp32 in/out.
//
// Round-9: attn REVERTED to the measured-best r6 version (185us; r7 reg-
// prefetch and r8 wave-split both regressed it -- r8 cost +113MB of K/V
// re-reads). pgemm restructured BARRIER-FREE: At staged once (1 barrier),
// then 4 mats of { B-frags direct from L2-hot Wt (r3-proven), MFMA, direct
// coalesced 2B global stores (16 lanes = dense 32B sector) }. No Bt, no Ct,
// no barriers in the mat loop -> LDS 32KB, ~16 independent wave streams/CU
// (was 2 lockstepped blocks x 16 barrier epochs).
// ln/out/prep/tri_tr byte-identical to r6 (477us config).
//
// prep:    transpose 5 weight mats to bf16 [n][k] B-frag layout; Q_SCALE in wq.
// ln:      LN (fp32) + tri bias; writes xn (bf16 [pos][c]) + tri [h][i][j].
// tri_tr:  in-place 32x32 tile-pair transpose per h: [h][i][j] -> [h][j][i].
// pgemm:   see above.
// attn:    MFMA flash attention per (i,h); kt tile in 3 passes of 2 m-tiles,
//          P scratch 32x68/wave; LDS 27.4KB -> 5 blocks/CU.  (r6 verbatim)
// out:     MFMA GEMM og x woT, staged Bt.  (r6 verbatim)
//
// LDS swizzle: row-major [row][128 bf16], 16 chunks of 8 bf16 at (c^(row&7)).

#define I_DIM 384
#define J_DIM 384
#define C_DIM 128
#define H_DIM 4
#define D_DIM 32
#define NPOS (I_DIM * J_DIM)
#define Q_SCALE 0.17677669529663687f  // 1/sqrt(32)

typedef __attribute__((ext_vector_type(8))) short bf16x8;
typedef __attribute__((ext_vector_type(4))) float f32x4;

__device__ __forceinline__ float sigmoidf_(float v) {
    return 1.0f / (1.0f + __expf(-v));
}
__device__ __forceinline__ unsigned short f2bf(float f) {
    union { float f; unsigned u; } x; x.f = f;
    unsigned u = x.u;
    u += 0x7fffu + ((u >> 16) & 1u);
    return (unsigned short)(u >> 16);
}
__device__ __forceinline__ float bf2f(unsigned short v) {
    union { unsigned u; float f; } x; x.u = ((unsigned)v) << 16;
    return x.f;
}

// ---------------------------------------------------------------------------
// prep: Wt[mat][n][k] = W[k*128+n] (bf16), mat 0..4 = wq,wk,wv,wg,wo.
// ---------------------------------------------------------------------------
__global__ __launch_bounds__(256) void prep_kernel(
    const float* __restrict__ wq, const float* __restrict__ wk,
    const float* __restrict__ wv, const float* __restrict__ wg,
    const float* __restrict__ wo, unsigned short* __restrict__ Wt)
{
    const int mat = blockIdx.x;
    const float* W = (mat == 0) ? wq : (mat == 1) ? wk : (mat == 2) ? wv
                    : (mat == 3) ? wg : wo;
    const float scale = (mat == 0) ? Q_SCALE : 1.0f;
    const int t = threadIdx.x;
    const int n = t >> 1, c0 = (t & 1) * 64;
#pragma unroll
    for (int u = 0; u < 8; ++u) {
        unsigned pk[4];
#pragma unroll
        for (int w = 0; w < 4; ++w) {
            const unsigned short a = f2bf(W[(size_t)(c0 + u * 8 + w * 2 + 0) * 128 + n] * scale);
            const unsigned short b = f2bf(W[(size_t)(c0 + u * 8 + w * 2 + 1) * 128 + n] * scale);
            pk[w] = (unsigned)a | ((unsigned)b << 16);
        }
        int4 q; q.x = pk[0]; q.y = pk[1]; q.z = pk[2]; q.w = pk[3];
        *(int4*)(Wt + (size_t)mat * 16384 + n * 128 + c0 + u * 8) = q;
    }
}

// ---------------------------------------------------------------------------
// ln: pure streaming LayerNorm + tri bias.  grid = NPOS/64 = 2304, block 256.
// 4 threads per row (q = 32-ch slice).  Writes xn bf16 [pos][c] + tri [h][i][j].
// ---------------------------------------------------------------------------
__global__ __launch_bounds__(256) void ln_kernel(
    const float* __restrict__ x, const float* __restrict__ ln_g,
    const float* __restrict__ ln_b, const float* __restrict__ w_tri,
    unsigned short* __restrict__ xn, float* __restrict__ tri)
{
    const int t = threadIdx.x;
    const int g = t >> 2, q = t & 3;
    const int pos = blockIdx.x * 64 + g;
    const float* xrow = x + (size_t)pos * C_DIM + q * 32;

    float xv[32];
    float s = 0.f, ss = 0.f;
#pragma unroll
    for (int u = 0; u < 8; ++u) {
        float4 v4 = ((const float4*)xrow)[u];
        xv[u * 4 + 0] = v4.x; xv[u * 4 + 1] = v4.y;
        xv[u * 4 + 2] = v4.z; xv[u * 4 + 3] = v4.w;
        s  += v4.x + v4.y + v4.z + v4.w;
        ss += v4.x * v4.x + v4.y * v4.y + v4.z * v4.z + v4.w * v4.w;
    }
    s  += __shfl_xor(s, 1);  s  += __shfl_xor(s, 2);
    ss += __shfl_xor(ss, 1); ss += __shfl_xor(ss, 2);
    const float mu  = s * (1.0f / 128.0f);
    const float var = ss * (1.0f / 128.0f) - mu * mu;
    const float rstd = rsqrtf(var + 1e-5f);

    float ptri[4] = {0.f, 0.f, 0.f, 0.f};
    unsigned short* xdst = xn + (size_t)pos * C_DIM + q * 32;
#pragma unroll
    for (int u2 = 0; u2 < 4; ++u2) {   // chunk of 8 channels
        const int cb = q * 32 + u2 * 8;
        const float4 g0 = *(const float4*)(ln_g + cb);
        const float4 g1 = *(const float4*)(ln_g + cb + 4);
        const float4 b0 = *(const float4*)(ln_b + cb);
        const float4 b1 = *(const float4*)(ln_b + cb + 4);
        float xn8[8];
        xn8[0] = (xv[u2 * 8 + 0] - mu) * rstd * g0.x + b0.x;
        xn8[1] = (xv[u2 * 8 + 1] - mu) * rstd * g0.y + b0.y;
        xn8[2] = (xv[u2 * 8 + 2] - mu) * rstd * g0.z + b0.z;
        xn8[3] = (xv[u2 * 8 + 3] - mu) * rstd * g0.w + b0.w;
        xn8[4] = (xv[u2 * 8 + 4] - mu) * rstd * g1.x + b1.x;
        xn8[5] = (xv[u2 * 8 + 5] - mu) * rstd * g1.y + b1.y;
        xn8[6] = (xv[u2 * 8 + 6] - mu) * rstd * g1.z + b1.z;
        xn8[7] = (xv[u2 * 8 + 7] - mu) * rstd * g1.w + b1.w;
#pragma unroll
        for (int w = 0; w < 8; ++w) {
            const float4 wt = ((const float4*)w_tri)[cb + w];
            ptri[0] += xn8[w] * wt.x; ptri[1] += xn8[w] * wt.y;
            ptri[2] += xn8[w] * wt.z; ptri[3] += xn8[w] * wt.w;
        }
        unsigned pk[4];
#pragma unroll
        for (int w = 0; w < 4; ++w)
            pk[w] = (unsigned)f2bf(xn8[w * 2]) | ((unsigned)f2bf(xn8[w * 2 + 1]) << 16);
        int4 q4; q4.x = pk[0]; q4.y = pk[1]; q4.z = pk[2]; q4.w = pk[3];
        *(int4*)(xdst + u2 * 8) = q4;
    }
#pragma unroll
    for (int hh = 0; hh < 4; ++hh) {
        ptri[hh] += __shfl_xor(ptri[hh], 1);
        ptri[hh] += __shfl_xor(ptri[hh], 2);
    }
    const int i = pos / J_DIM, j = pos - (pos / J_DIM) * J_DIM;
    tri[((size_t)q * I_DIM + i) * J_DIM + j] = ptri[q];
}

// ---------------------------------------------------------------------------
// tri_tr: in-place transpose [h][i][j] -> [h][j][i].  32x32 fp32 tile pairs.
// grid = H * 78 (78 = 12*13/2 triangular tile pairs), block = 256.
// ---------------------------------------------------------------------------
__global__ __launch_bounds__(256) void tri_tr_kernel(float* __restrict__ tri)
{
    const int h = blockIdx.x / 78;
    int rem = blockIdx.x - h * 78;
    int ti = 0;
    while (rem >= 12 - ti) { rem -= 12 - ti; ++ti; }
    const int tj = ti + rem;

    float* T = tri + (size_t)h * I_DIM * J_DIM;
    __shared__ float A[32][33];
    __shared__ float B[32][33];

    const int t = threadIdx.x;
    const int r = t >> 3, c4 = (t & 7) * 4;

    {
        const float4 v = *(const float4*)(T + (size_t)(ti * 32 + r) * J_DIM + tj * 32 + c4);
        A[r][c4 + 0] = v.x; A[r][c4 + 1] = v.y; A[r][c4 + 2] = v.z; A[r][c4 + 3] = v.w;
        const float4 w = *(const float4*)(T + (size_t)(tj * 32 + r) * J_DIM + ti * 32 + c4);
        B[r][c4 + 0] = w.x; B[r][c4 + 1] = w.y; B[r][c4 + 2] = w.z; B[r][c4 + 3] = w.w;
    }
    __syncthreads();
    {
        float4 v;
        v.x = B[c4 + 0][r]; v.y = B[c4 + 1][r]; v.z = B[c4 + 2][r]; v.w = B[c4 + 3][r];
        *(float4*)(T + (size_t)(ti * 32 + r) * J_DIM + tj * 32 + c4) = v;
        float4 w;
        w.x = A[c4 + 0][r]; w.y = A[c4 + 1][r]; w.z = A[c4 + 2][r]; w.w = A[c4 + 3][r];
        *(float4*)(T + (size_t)(tj * 32 + r) * J_DIM + ti * 32 + c4) = w;
    }
}

// ---------------------------------------------------------------------------
// pgemm: 4 MFMA GEMMs from xn.  grid = NPOS/128 = 1152, block = 256.
// Barrier-free: At staged once (1 barrier); per mat, B-frags DIRECT from
// L2-hot Wt, MFMA, then direct global stores (16 q15-lanes = dense 32B
// sector).  LDS = At only (32KB); waves fully independent after the stage.
// ---------------------------------------------------------------------------
__global__ __launch_bounds__(256) void pgemm_kernel(
    const unsigned short* __restrict__ xn, const unsigned short* __restrict__ Wt,
    const float* __restrict__ bg,
    unsigned short* __restrict__ qb, unsigned short* __restrict__ kb,
    unsigned short* __restrict__ vb, unsigned short* __restrict__ gb)
{
    __shared__ unsigned short At[128 * 128];

    const int t = threadIdx.x;
    const int pos0 = blockIdx.x * 128;
    const int lane = t & 63, wave = t >> 6;
    const int q15 = lane & 15, quad = lane >> 4;

    // ---- stage At (swizzled) from xn ----
    {
        const int r = t >> 1, half = t & 1;
        const unsigned short* src = xn + (size_t)(pos0 + r) * C_DIM + half * 64;
#pragma unroll
        for (int u = 0; u < 8; ++u) {
            const int c = half * 8 + u;
            *(int4*)&At[r * 128 + ((c ^ (r & 7)) * 8)] = *(const int4*)(src + u * 8);
        }
    }
    __syncthreads();   // the only barrier

    const int m0 = wave * 32;
    for (int mat = 0; mat < 4; ++mat) {
        const unsigned short* WtM = Wt + (size_t)mat * 16384;

        f32x4 acc[2][8];
#pragma unroll
        for (int mt = 0; mt < 2; ++mt)
#pragma unroll
            for (int nt = 0; nt < 8; ++nt) acc[mt][nt] = (f32x4){0.f, 0.f, 0.f, 0.f};

#pragma unroll
        for (int kk = 0; kk < 4; ++kk) {
            // all hot rows are ≡ q15 (mod 16) -> row&7 == q15&7 -> common swizzle
            const int sw = ((kk * 4 + quad) ^ (q15 & 7)) * 8;
            const bf16x8 a0 = *(const bf16x8*)&At[(m0 + q15) * 128 + sw];
            const bf16x8 a1 = *(const bf16x8*)&At[(m0 + 16 + q15) * 128 + sw];
            const unsigned short* bp = WtM + q15 * 128 + (kk * 4 + quad) * 8;
#pragma unroll
            for (int nt = 0; nt < 8; ++nt) {
                const bf16x8 b = *(const bf16x8*)(bp + nt * 16 * 128);
                acc[0][nt] = __builtin_amdgcn_mfma_f32_16x16x32_bf16(a0, b, acc[0][nt], 0, 0, 0);
                acc[1][nt] = __builtin_amdgcn_mfma_f32_16x16x32_bf16(a1, b, acc[1][nt], 0, 0, 0);
            }
        }

        // ---- epilogue: direct global stores, no LDS, no barrier ----
        unsigned short* O = (mat == 0) ? qb : (mat == 1) ? kb : (mat == 2) ? vb : gb;
#pragma unroll
        for (int mt = 0; mt < 2; ++mt)
#pragma unroll
            for (int reg = 0; reg < 4; ++reg) {
                const int pos = pos0 + m0 + mt * 16 + quad * 4 + reg;
                const int i = pos / J_DIM, j = pos - (pos / J_DIM) * J_DIM;
                unsigned short* rowp = O + ((size_t)i * H_DIM * J_DIM + j) * D_DIM;
#pragma unroll
                for (int nt = 0; nt < 8; ++nt) {
                    float v = acc[mt][nt][reg];
                    if (mat == 3) v = sigmoidf_(v + bg[nt * 16 + q15]);
                    rowp[(nt >> 1) * (J_DIM * D_DIM) + (nt & 1) * 16 + q15] = f2bf(v);
                }
            }
    }
}

// ---------------------------------------------------------------------------
// attn: MFMA flash attention.  grid = I*H = 1536, block = 256 (4 waves).
// kt tile in 3 passes x 2 m-tiles; P scratch 32x68/wave.  (r6 verbatim)
// LDS = 4K (K) + 4.3K (Vt) + 17.4K (P) + 1.5K (Mb) = 27.4KB -> 5 blocks/CU.
// ---------------------------------------------------------------------------
__global__ __launch_bounds__(256) void attn_kernel(
    const unsigned short* __restrict__ qb, const unsigned short* __restrict__ kb,
    const unsigned short* __restrict__ vb, unsigned short* gob,
    const float* __restrict__ triT, const float* __restrict__ mask)
{
    __shared__ unsigned short Klds[64 * 32];
    __shared__ unsigned short Vt[32 * 68];
    __shared__ unsigned short Plds[4][32 * 68];
    __shared__ float Mb[J_DIM];

    const int t = threadIdx.x;
    const int lane = t & 63, wave = t >> 6;
    const int q15 = lane & 15, quad = lane >> 4;
    const int i = blockIdx.x >> 2, h = blockIdx.x & 3;
    const size_t hb = (size_t)(i * H_DIM + h) * (J_DIM * D_DIM);
    const int m0 = wave * 96;

    for (int idx = t; idx < J_DIM; idx += 256)
        Mb[idx] = 1.0e9f * (mask[i * J_DIM + idx] - 1.0f);

    bf16x8 qf[6];
#pragma unroll
    for (int m = 0; m < 6; ++m)
        qf[m] = *(const bf16x8*)(qb + hb + (size_t)(m0 + m * 16 + q15) * D_DIM + quad * 8);

    f32x4 Oacc[6][2];
    float sums[6][4];
#pragma unroll
    for (int m = 0; m < 6; ++m) {
#pragma unroll
        for (int d2 = 0; d2 < 2; ++d2) Oacc[m][d2] = (f32x4){0.f, 0.f, 0.f, 0.f};
#pragma unroll
        for (int r = 0; r < 4; ++r) sums[m][r] = 0.f;
    }

    unsigned short* Pw = Plds[wave];
    const float* triH = triT + (size_t)h * J_DIM * I_DIM;

    for (int kt = 0; kt < 6; ++kt) {
        __syncthreads();
        {
            const int kp = t >> 2, du = (t & 3) * 8;
            const size_t gsrc = hb + (size_t)(kt * 64 + kp) * D_DIM + du;
            *(int4*)&Klds[kp * 32 + du] = *(const int4*)(kb + gsrc);
            int4 vv = *(const int4*)(vb + gsrc);
            const unsigned short* vs = (const unsigned short*)&vv;
#pragma unroll
            for (int u = 0; u < 8; ++u)
                Vt[(du + u) * 68 + kp] = vs[u];
        }
        __syncthreads();

        // V fragments for this kt (reused by all 3 passes)
        bf16x8 vf[2][2];
#pragma unroll
        for (int ks = 0; ks < 2; ++ks)
#pragma unroll
            for (int d2 = 0; d2 < 2; ++d2)
                vf[ks][d2] = *(const bf16x8*)&Vt[(d2 * 16 + q15) * 68 + ks * 32 + quad * 8];

#pragma unroll
        for (int pass = 0; pass < 3; ++pass) {
            const int mbase = pass * 2;

            // ---- QK^T + exp for 2 m-tiles (nt-outer, kf loaded once/nt) ----
#pragma unroll
            for (int nt = 0; nt < 4; ++nt) {
                const bf16x8 kf = *(const bf16x8*)&Klds[(nt * 16 + q15) * 32 + quad * 8];
                const float mb = Mb[kt * 64 + nt * 16 + q15];
                const float* tcol = triH + (size_t)(kt * 64 + nt * 16 + q15) * I_DIM;
#pragma unroll
                for (int mm = 0; mm < 2; ++mm) {
                    const int m = mbase + mm;
                    const float4 tb = *(const float4*)(tcol + m0 + m * 16 + quad * 4);
                    f32x4 s = {0.f, 0.f, 0.f, 0.f};
                    s = __builtin_amdgcn_mfma_f32_16x16x32_bf16(qf[m], kf, s, 0, 0, 0);
                    const float p0 = __expf(s[0] + mb + tb.x);
                    const float p1 = __expf(s[1] + mb + tb.y);
                    const float p2 = __expf(s[2] + mb + tb.z);
                    const float p3 = __expf(s[3] + mb + tb.w);
                    sums[m][0] += p0; sums[m][1] += p1;
                    sums[m][2] += p2; sums[m][3] += p3;
                    const int row = mm * 16 + quad * 4;
                    const int col = nt * 16 + q15;
                    Pw[(row + 0) * 68 + col] = f2bf(p0);
                    Pw[(row + 1) * 68 + col] = f2bf(p1);
                    Pw[(row + 2) * 68 + col] = f2bf(p2);
                    Pw[(row + 3) * 68 + col] = f2bf(p3);
                }
            }

            // ---- PV for those 2 m-tiles (wave-local P, no barrier needed) ----
#pragma unroll
            for (int mm = 0; mm < 2; ++mm) {
                const int m = mbase + mm;
#pragma unroll
                for (int ks = 0; ks < 2; ++ks) {
                    const bf16x8 af = *(const bf16x8*)&Pw[(mm * 16 + q15) * 68 + ks * 32 + quad * 8];
                    Oacc[m][0] = __builtin_amdgcn_mfma_f32_16x16x32_bf16(af, vf[ks][0], Oacc[m][0], 0, 0, 0);
                    Oacc[m][1] = __builtin_amdgcn_mfma_f32_16x16x32_bf16(af, vf[ks][1], Oacc[m][1], 0, 0, 0);
                }
            }
        }
    }

    float inv[6][4];
#pragma unroll
    for (int m = 0; m < 6; ++m)
#pragma unroll
        for (int r = 0; r < 4; ++r) {
            float s0 = sums[m][r];
            s0 += __shfl_xor(s0, 1); s0 += __shfl_xor(s0, 2);
            s0 += __shfl_xor(s0, 4); s0 += __shfl_xor(s0, 8);
            inv[m][r] = 1.0f / s0;
        }

#pragma unroll
    for (int m = 0; m < 6; ++m) {
        const int qrow = m0 + m * 16 + quad * 4;
#pragma unroll
        for (int d2 = 0; d2 < 2; ++d2) {
            const int d = d2 * 16 + q15;
#pragma unroll
            for (int r = 0; r < 4; ++r) {
                const size_t idx = hb + (size_t)(qrow + r) * D_DIM + d;
                const float g = bf2f(gob[idx]);
                gob[idx] = f2bf(Oacc[m][d2][r] * inv[m][r] * g);
            }
        }
    }
}

// ---------------------------------------------------------------------------
// out: MFMA GEMM.  grid = NPOS/128 = 1152, block = 256.  (r2 staged verbatim)
// ---------------------------------------------------------------------------
__global__ __launch_bounds__(256) void out_kernel(
    const unsigned short* __restrict__ og, const unsigned short* __restrict__ WtO,
    const float* __restrict__ bo, float* __restrict__ out)
{
    __shared__ unsigned short At[128 * 128];
    __shared__ unsigned short Bt[128 * 128];

    const int t = threadIdx.x;
    const int pos0 = blockIdx.x * 128;
    const int lane = t & 63, wave = t >> 6;
    const int q15 = lane & 15, quad = lane >> 4;

    {
        const int r = t >> 1, half = t & 1;
        const int pos = pos0 + r;
        const int i = pos / J_DIM, j = pos - (pos / J_DIM) * J_DIM;
#pragma unroll
        for (int u = 0; u < 8; ++u) {
            const int k0 = half * 64 + u * 8;
            const int hh = k0 >> 5, d0 = k0 & 31;
            const int4 v = *(const int4*)(og + (((size_t)i * H_DIM + hh) * J_DIM + j) * D_DIM + d0);
            const int c = half * 8 + u;
            *(int4*)&At[r * 128 + ((c ^ (r & 7)) * 8)] = v;
        }
        const unsigned short* src = WtO + r * 128 + half * 64;
#pragma unroll
        for (int u = 0; u < 8; ++u) {
            const int c = half * 8 + u;
            *(int4*)&Bt[r * 128 + ((c ^ (r & 7)) * 8)] = *(const int4*)(src + u * 8);
        }
    }
    __syncthreads();

    const int m0 = wave * 32;
    f32x4 acc[2][8];
#pragma unroll
    for (int mt = 0; mt < 2; ++mt)
#pragma unroll
        for (int nt = 0; nt < 8; ++nt) acc[mt][nt] = (f32x4){0.f, 0.f, 0.f, 0.f};

#pragma unroll
    for (int kk = 0; kk < 4; ++kk) {
        const int sw = ((kk * 4 + quad) ^ (q15 & 7)) * 8;
        const bf16x8 a0 = *(const bf16x8*)&At[(m0 + q15) * 128 + sw];
        const bf16x8 a1 = *(const bf16x8*)&At[(m0 + 16 + q15) * 128 + sw];
#pragma unroll
        for (int nt = 0; nt < 8; ++nt) {
            const bf16x8 b = *(const bf16x8*)&Bt[(nt * 16 + q15) * 128 + sw];
            acc[0][nt] = __builtin_amdgcn_mfma_f32_16x16x32_bf16(a0, b, acc[0][nt], 0, 0, 0);
            acc[1][nt] = __builtin_amdgcn_mfma_f32_16x16x32_bf16(a1, b, acc[1][nt], 0, 0, 0);
        }
    }

#pragma unroll
    for (int mt = 0; mt < 2; ++mt)
#pragma unroll
        for (int nt = 0; nt < 8; ++nt) {
            const float bov = bo[nt * 16 + q15];
#pragma unroll
            for (int reg = 0; reg < 4; ++reg) {
                const int pos = pos0 + m0 + mt * 16 + quad * 4 + reg;
                out[(size_t)pos * C_DIM + nt * 16 + q15] = acc[mt][nt][reg] + bov;
            }
        }
}

// ---------------------------------------------------------------------------
extern "C" void kernel_launch(void* const* d_in, const int* in_sizes, int n_in,
                              void* d_out, int out_size, void* d_ws, size_t ws_size,
                              hipStream_t stream)
{
    const float* x     = (const float*)d_in[0];
    const float* mask  = (const float*)d_in[1];
    const float* ln_g  = (const float*)d_in[2];
    const float* ln_b  = (const float*)d_in[3];
    const float* w_tri = (const float*)d_in[4];
    const float* wq    = (const float*)d_in[5];
    const float* wk    = (const float*)d_in[6];
    const float* wv    = (const float*)d_in[7];
    const float* wg    = (const float*)d_in[8];
    const float* bg    = (const float*)d_in[9];
    const float* wo    = (const float*)d_in[10];
    const float* bo    = (const float*)d_in[11];
    float* out = (float*)d_out;
    char* ws = (char*)d_ws;

    const size_t NE = (size_t)NPOS * 128;   // elements per [I,H,J,D] buffer
    unsigned short* qb = (unsigned short*)ws;                     // bf16 36 MiB
    unsigned short* kb = (unsigned short*)(ws + NE * 2);
    unsigned short* vb = (unsigned short*)(ws + NE * 4);
    unsigned short* gb = (unsigned short*)(ws + NE * 6);          // g -> og
    float*         tri = (float*)(ws + NE * 8);                   // [H][.][.]
    unsigned short* Wt = (unsigned short*)(ws + NE * 8 + (size_t)NPOS * 4 * 4);
    unsigned short* xn = Wt + 5 * 16384;                          // bf16 [pos][c]

    prep_kernel<<<5, 256, 0, stream>>>(wq, wk, wv, wg, wo, Wt);
    ln_kernel<<<NPOS / 64, 256, 0, stream>>>(x, ln_g, ln_b, w_tri, xn, tri);
    tri_tr_kernel<<<H_DIM * 78, 256, 0, stream>>>(tri);
    pgemm_kernel<<<NPOS / 128, 256, 0, stream>>>(xn, Wt, bg, qb, kb, vb, gb);
    attn_kernel<<<I_DIM * H_DIM, 256, 0, stream>>>(qb, kb, vb, gb, tri, mask);
    out_kernel<<<NPOS / 128, 256, 0, stream>>>(gb, Wt + 4 * 16384, bo, out);
}

// Round 10
// 476.122 us; speedup vs baseline: 1.1104x; 1.1104x over previous
//
#include <hip/hip_runtime.h>
#include <math.h>

// TriangleAttention: B=1, I=J=384, C=128, H=4, D=32, fp32 in/out.
//
// Round-10: restore measured-best r6 config (477us) -- pgemm back to the
// staged-Bt/staged-epilogue version (r9's direct 2B stores cost +52us).
// Only change vs r6: ln writes tri DIRECTLY in attn's [h][j][i] layout
// (scattered 4B stores, the exact pattern proj used in r0-r3 at no cost),
// eliminating the tri_tr kernel and its 9.4MB round-trip.
//
// prep:    transpose 5 weight mats to bf16 [n][k] B-frag layout; Q_SCALE in wq.
// ln:      LN (fp32) + tri bias; writes xn (bf16 [pos][c], coalesced) and tri
//          [h][j][i] (scattered, proven-neutral).
// pgemm:   per 128-row tile: stage At from xn; 4x { stage Bt from L2-hot Wt;
//          MFMA 16x16x32; epilogue C->Bt(bf16) -> coalesced global }. (r6)
// attn:    MFMA flash attention per (i,h); kt tile in 3 passes of 2 m-tiles,
//          P scratch 32x68/wave; LDS 27.4KB -> 5 blocks/CU.  (r6 verbatim;
//          r7 reg-prefetch, r8 wave-split both measured worse -- frozen)
// out:     MFMA GEMM og x woT, staged Bt.  (r6 verbatim)
//
// LDS swizzle: row-major [row][128 bf16], 16 chunks of 8 bf16 at (c^(row&7)).

#define I_DIM 384
#define J_DIM 384
#define C_DIM 128
#define H_DIM 4
#define D_DIM 32
#define NPOS (I_DIM * J_DIM)
#define Q_SCALE 0.17677669529663687f  // 1/sqrt(32)

typedef __attribute__((ext_vector_type(8))) short bf16x8;
typedef __attribute__((ext_vector_type(4))) float f32x4;

__device__ __forceinline__ float sigmoidf_(float v) {
    return 1.0f / (1.0f + __expf(-v));
}
__device__ __forceinline__ unsigned short f2bf(float f) {
    union { float f; unsigned u; } x; x.f = f;
    unsigned u = x.u;
    u += 0x7fffu + ((u >> 16) & 1u);
    return (unsigned short)(u >> 16);
}
__device__ __forceinline__ float bf2f(unsigned short v) {
    union { unsigned u; float f; } x; x.u = ((unsigned)v) << 16;
    return x.f;
}

// ---------------------------------------------------------------------------
// prep: Wt[mat][n][k] = W[k*128+n] (bf16), mat 0..4 = wq,wk,wv,wg,wo.
// ---------------------------------------------------------------------------
__global__ __launch_bounds__(256) void prep_kernel(
    const float* __restrict__ wq, const float* __restrict__ wk,
    const float* __restrict__ wv, const float* __restrict__ wg,
    const float* __restrict__ wo, unsigned short* __restrict__ Wt)
{
    const int mat = blockIdx.x;
    const float* W = (mat == 0) ? wq : (mat == 1) ? wk : (mat == 2) ? wv
                    : (mat == 3) ? wg : wo;
    const float scale = (mat == 0) ? Q_SCALE : 1.0f;
    const int t = threadIdx.x;
    const int n = t >> 1, c0 = (t & 1) * 64;
#pragma unroll
    for (int u = 0; u < 8; ++u) {
        unsigned pk[4];
#pragma unroll
        for (int w = 0; w < 4; ++w) {
            const unsigned short a = f2bf(W[(size_t)(c0 + u * 8 + w * 2 + 0) * 128 + n] * scale);
            const unsigned short b = f2bf(W[(size_t)(c0 + u * 8 + w * 2 + 1) * 128 + n] * scale);
            pk[w] = (unsigned)a | ((unsigned)b << 16);
        }
        int4 q; q.x = pk[0]; q.y = pk[1]; q.z = pk[2]; q.w = pk[3];
        *(int4*)(Wt + (size_t)mat * 16384 + n * 128 + c0 + u * 8) = q;
    }
}

// ---------------------------------------------------------------------------
// ln: pure streaming LayerNorm + tri bias.  grid = NPOS/64 = 2304, block 256.
// 4 threads per row (q = 32-ch slice).  Writes xn bf16 [pos][c] (coalesced)
// + tri [h][j][i] directly (scattered 4B, proven-neutral in r0-r3 proj).
// ---------------------------------------------------------------------------
__global__ __launch_bounds__(256) void ln_kernel(
    const float* __restrict__ x, const float* __restrict__ ln_g,
    const float* __restrict__ ln_b, const float* __restrict__ w_tri,
    unsigned short* __restrict__ xn, float* __restrict__ tri)
{
    const int t = threadIdx.x;
    const int g = t >> 2, q = t & 3;
    const int pos = blockIdx.x * 64 + g;
    const float* xrow = x + (size_t)pos * C_DIM + q * 32;

    float xv[32];
    float s = 0.f, ss = 0.f;
#pragma unroll
    for (int u = 0; u < 8; ++u) {
        float4 v4 = ((const float4*)xrow)[u];
        xv[u * 4 + 0] = v4.x; xv[u * 4 + 1] = v4.y;
        xv[u * 4 + 2] = v4.z; xv[u * 4 + 3] = v4.w;
        s  += v4.x + v4.y + v4.z + v4.w;
        ss += v4.x * v4.x + v4.y * v4.y + v4.z * v4.z + v4.w * v4.w;
    }
    s  += __shfl_xor(s, 1);  s  += __shfl_xor(s, 2);
    ss += __shfl_xor(ss, 1); ss += __shfl_xor(ss, 2);
    const float mu  = s * (1.0f / 128.0f);
    const float var = ss * (1.0f / 128.0f) - mu * mu;
    const float rstd = rsqrtf(var + 1e-5f);

    float ptri[4] = {0.f, 0.f, 0.f, 0.f};
    unsigned short* xdst = xn + (size_t)pos * C_DIM + q * 32;
#pragma unroll
    for (int u2 = 0; u2 < 4; ++u2) {   // chunk of 8 channels
        const int cb = q * 32 + u2 * 8;
        const float4 g0 = *(const float4*)(ln_g + cb);
        const float4 g1 = *(const float4*)(ln_g + cb + 4);
        const float4 b0 = *(const float4*)(ln_b + cb);
        const float4 b1 = *(const float4*)(ln_b + cb + 4);
        float xn8[8];
        xn8[0] = (xv[u2 * 8 + 0] - mu) * rstd * g0.x + b0.x;
        xn8[1] = (xv[u2 * 8 + 1] - mu) * rstd * g0.y + b0.y;
        xn8[2] = (xv[u2 * 8 + 2] - mu) * rstd * g0.z + b0.z;
        xn8[3] = (xv[u2 * 8 + 3] - mu) * rstd * g0.w + b0.w;
        xn8[4] = (xv[u2 * 8 + 4] - mu) * rstd * g1.x + b1.x;
        xn8[5] = (xv[u2 * 8 + 5] - mu) * rstd * g1.y + b1.y;
        xn8[6] = (xv[u2 * 8 + 6] - mu) * rstd * g1.z + b1.z;
        xn8[7] = (xv[u2 * 8 + 7] - mu) * rstd * g1.w + b1.w;
#pragma unroll
        for (int w = 0; w < 8; ++w) {
            const float4 wt = ((const float4*)w_tri)[cb + w];
            ptri[0] += xn8[w] * wt.x; ptri[1] += xn8[w] * wt.y;
            ptri[2] += xn8[w] * wt.z; ptri[3] += xn8[w] * wt.w;
        }
        unsigned pk[4];
#pragma unroll
        for (int w = 0; w < 4; ++w)
            pk[w] = (unsigned)f2bf(xn8[w * 2]) | ((unsigned)f2bf(xn8[w * 2 + 1]) << 16);
        int4 q4; q4.x = pk[0]; q4.y = pk[1]; q4.z = pk[2]; q4.w = pk[3];
        *(int4*)(xdst + u2 * 8) = q4;
    }
#pragma unroll
    for (int hh = 0; hh < 4; ++hh) {
        ptri[hh] += __shfl_xor(ptri[hh], 1);
        ptri[hh] += __shfl_xor(ptri[hh], 2);
    }
    const int i = pos / J_DIM, j = pos - (pos / J_DIM) * J_DIM;
    // direct [h][j][i] write (attn's consumption layout); scatter stride
    // 1536B -- measured-neutral in the r0-r3 fused proj.
    tri[((size_t)q * J_DIM + j) * I_DIM + i] = ptri[q];
}

// ---------------------------------------------------------------------------
// pgemm: 4 MFMA GEMMs from xn.  grid = NPOS/128 = 1152, block = 256.
// LDS 64KB (At + Bt, Ct reuses Bt) -> 2 blocks/CU.  (r6 verbatim)
// ---------------------------------------------------------------------------
__global__ __launch_bounds__(256) void pgemm_kernel(
    const unsigned short* __restrict__ xn, const unsigned short* __restrict__ Wt,
    const float* __restrict__ bg,
    unsigned short* __restrict__ qb, unsigned short* __restrict__ kb,
    unsigned short* __restrict__ vb, unsigned short* __restrict__ gb)
{
    __shared__ unsigned short At[128 * 128];
    __shared__ unsigned short Bt[128 * 128];

    const int t = threadIdx.x;
    const int pos0 = blockIdx.x * 128;
    const int lane = t & 63, wave = t >> 6;
    const int q15 = lane & 15, quad = lane >> 4;

    // ---- stage At (swizzled) from xn ----
    {
        const int r = t >> 1, half = t & 1;
        const unsigned short* src = xn + (size_t)(pos0 + r) * C_DIM + half * 64;
#pragma unroll
        for (int u = 0; u < 8; ++u) {
            const int c = half * 8 + u;
            *(int4*)&At[r * 128 + ((c ^ (r & 7)) * 8)] = *(const int4*)(src + u * 8);
        }
    }

    const int m0 = wave * 32;
    for (int mat = 0; mat < 4; ++mat) {
        __syncthreads();
        // ---- stage B-tile (swizzled) ----
        {
            const int rn = t >> 1, half = t & 1;
            const unsigned short* src = Wt + (size_t)mat * 16384 + rn * 128 + half * 64;
#pragma unroll
            for (int u = 0; u < 8; ++u) {
                const int c = half * 8 + u;
                *(int4*)&Bt[rn * 128 + ((c ^ (rn & 7)) * 8)] = *(const int4*)(src + u * 8);
            }
        }
        __syncthreads();

        f32x4 acc[2][8];
#pragma unroll
        for (int mt = 0; mt < 2; ++mt)
#pragma unroll
            for (int nt = 0; nt < 8; ++nt) acc[mt][nt] = (f32x4){0.f, 0.f, 0.f, 0.f};

#pragma unroll
        for (int kk = 0; kk < 4; ++kk) {
            // all hot rows are ≡ q15 (mod 16) -> row&7 == q15&7 -> common swizzle
            const int sw = ((kk * 4 + quad) ^ (q15 & 7)) * 8;
            const bf16x8 a0 = *(const bf16x8*)&At[(m0 + q15) * 128 + sw];
            const bf16x8 a1 = *(const bf16x8*)&At[(m0 + 16 + q15) * 128 + sw];
#pragma unroll
            for (int nt = 0; nt < 8; ++nt) {
                const bf16x8 b = *(const bf16x8*)&Bt[(nt * 16 + q15) * 128 + sw];
                acc[0][nt] = __builtin_amdgcn_mfma_f32_16x16x32_bf16(a0, b, acc[0][nt], 0, 0, 0);
                acc[1][nt] = __builtin_amdgcn_mfma_f32_16x16x32_bf16(a1, b, acc[1][nt], 0, 0, 0);
            }
        }

        // ---- epilogue: C -> Bt (bf16, swizzled) -> vectorized global ----
        __syncthreads();
#pragma unroll
        for (int mt = 0; mt < 2; ++mt)
#pragma unroll
            for (int nt = 0; nt < 8; ++nt) {
                const int col = nt * 16 + q15;
                const float bgl = (mat == 3) ? bg[col] : 0.f;
#pragma unroll
                for (int reg = 0; reg < 4; ++reg) {
                    float v = acc[mt][nt][reg];
                    if (mat == 3) v = sigmoidf_(v + bgl);
                    const int row = m0 + mt * 16 + quad * 4 + reg;
                    Bt[row * 128 + (((col >> 3) ^ (row & 7)) * 8) + (col & 7)] = f2bf(v);
                }
            }
        __syncthreads();
        {
            unsigned short* O = (mat == 0) ? qb : (mat == 1) ? kb : (mat == 2) ? vb : gb;
#pragma unroll
            for (int sgm = 0; sgm < 2; ++sgm) {
                const int ch = t + sgm * 256;       // 512 chunks = 128 rows x 4 heads
                const int r = ch >> 2, hh = ch & 3;
                const int pos = pos0 + r;
                const int i = pos / J_DIM, j = pos - (pos / J_DIM) * J_DIM;
                unsigned short* dst = O + (((size_t)i * H_DIM + hh) * J_DIM + j) * D_DIM;
#pragma unroll
                for (int w = 0; w < 4; ++w) {
                    const int c = hh * 4 + w;
                    *(int4*)(dst + w * 8) = *(const int4*)&Bt[r * 128 + ((c ^ (r & 7)) * 8)];
                }
            }
        }
    }
}

// ---------------------------------------------------------------------------
// attn: MFMA flash attention.  grid = I*H = 1536, block = 256 (4 waves).
// kt tile in 3 passes x 2 m-tiles; P scratch 32x68/wave.  (r6 verbatim)
// LDS = 4K (K) + 4.3K (Vt) + 17.4K (P) + 1.5K (Mb) = 27.4KB -> 5 blocks/CU.
// ---------------------------------------------------------------------------
__global__ __launch_bounds__(256) void attn_kernel(
    const unsigned short* __restrict__ qb, const unsigned short* __restrict__ kb,
    const unsigned short* __restrict__ vb, unsigned short* gob,
    const float* __restrict__ triT, const float* __restrict__ mask)
{
    __shared__ unsigned short Klds[64 * 32];
    __shared__ unsigned short Vt[32 * 68];
    __shared__ unsigned short Plds[4][32 * 68];
    __shared__ float Mb[J_DIM];

    const int t = threadIdx.x;
    const int lane = t & 63, wave = t >> 6;
    const int q15 = lane & 15, quad = lane >> 4;
    const int i = blockIdx.x >> 2, h = blockIdx.x & 3;
    const size_t hb = (size_t)(i * H_DIM + h) * (J_DIM * D_DIM);
    const int m0 = wave * 96;

    for (int idx = t; idx < J_DIM; idx += 256)
        Mb[idx] = 1.0e9f * (mask[i * J_DIM + idx] - 1.0f);

    bf16x8 qf[6];
#pragma unroll
    for (int m = 0; m < 6; ++m)
        qf[m] = *(const bf16x8*)(qb + hb + (size_t)(m0 + m * 16 + q15) * D_DIM + quad * 8);

    f32x4 Oacc[6][2];
    float sums[6][4];
#pragma unroll
    for (int m = 0; m < 6; ++m) {
#pragma unroll
        for (int d2 = 0; d2 < 2; ++d2) Oacc[m][d2] = (f32x4){0.f, 0.f, 0.f, 0.f};
#pragma unroll
        for (int r = 0; r < 4; ++r) sums[m][r] = 0.f;
    }

    unsigned short* Pw = Plds[wave];
    const float* triH = triT + (size_t)h * J_DIM * I_DIM;

    for (int kt = 0; kt < 6; ++kt) {
        __syncthreads();
        {
            const int kp = t >> 2, du = (t & 3) * 8;
            const size_t gsrc = hb + (size_t)(kt * 64 + kp) * D_DIM + du;
            *(int4*)&Klds[kp * 32 + du] = *(const int4*)(kb + gsrc);
            int4 vv = *(const int4*)(vb + gsrc);
            const unsigned short* vs = (const unsigned short*)&vv;
#pragma unroll
            for (int u = 0; u < 8; ++u)
                Vt[(du + u) * 68 + kp] = vs[u];
        }
        __syncthreads();

        // V fragments for this kt (reused by all 3 passes)
        bf16x8 vf[2][2];
#pragma unroll
        for (int ks = 0; ks < 2; ++ks)
#pragma unroll
            for (int d2 = 0; d2 < 2; ++d2)
                vf[ks][d2] = *(const bf16x8*)&Vt[(d2 * 16 + q15) * 68 + ks * 32 + quad * 8];

#pragma unroll
        for (int pass = 0; pass < 3; ++pass) {
            const int mbase = pass * 2;

            // ---- QK^T + exp for 2 m-tiles (nt-outer, kf loaded once/nt) ----
#pragma unroll
            for (int nt = 0; nt < 4; ++nt) {
                const bf16x8 kf = *(const bf16x8*)&Klds[(nt * 16 + q15) * 32 + quad * 8];
                const float mb = Mb[kt * 64 + nt * 16 + q15];
                const float* tcol = triH + (size_t)(kt * 64 + nt * 16 + q15) * I_DIM;
#pragma unroll
                for (int mm = 0; mm < 2; ++mm) {
                    const int m = mbase + mm;
                    const float4 tb = *(const float4*)(tcol + m0 + m * 16 + quad * 4);
                    f32x4 s = {0.f, 0.f, 0.f, 0.f};
                    s = __builtin_amdgcn_mfma_f32_16x16x32_bf16(qf[m], kf, s, 0, 0, 0);
                    const float p0 = __expf(s[0] + mb + tb.x);
                    const float p1 = __expf(s[1] + mb + tb.y);
                    const float p2 = __expf(s[2] + mb + tb.z);
                    const float p3 = __expf(s[3] + mb + tb.w);
                    sums[m][0] += p0; sums[m][1] += p1;
                    sums[m][2] += p2; sums[m][3] += p3;
                    const int row = mm * 16 + quad * 4;
                    const int col = nt * 16 + q15;
                    Pw[(row + 0) * 68 + col] = f2bf(p0);
                    Pw[(row + 1) * 68 + col] = f2bf(p1);
                    Pw[(row + 2) * 68 + col] = f2bf(p2);
                    Pw[(row + 3) * 68 + col] = f2bf(p3);
                }
            }

            // ---- PV for those 2 m-tiles (wave-local P, no barrier needed) ----
#pragma unroll
            for (int mm = 0; mm < 2; ++mm) {
                const int m = mbase + mm;
#pragma unroll
                for (int ks = 0; ks < 2; ++ks) {
                    const bf16x8 af = *(const bf16x8*)&Pw[(mm * 16 + q15) * 68 + ks * 32 + quad * 8];
                    Oacc[m][0] = __builtin_amdgcn_mfma_f32_16x16x32_bf16(af, vf[ks][0], Oacc[m][0], 0, 0, 0);
                    Oacc[m][1] = __builtin_amdgcn_mfma_f32_16x16x32_bf16(af, vf[ks][1], Oacc[m][1], 0, 0, 0);
                }
            }
        }
    }

    float inv[6][4];
#pragma unroll
    for (int m = 0; m < 6; ++m)
#pragma unroll
        for (int r = 0; r < 4; ++r) {
            float s0 = sums[m][r];
            s0 += __shfl_xor(s0, 1); s0 += __shfl_xor(s0, 2);
            s0 += __shfl_xor(s0, 4); s0 += __shfl_xor(s0, 8);
            inv[m][r] = 1.0f / s0;
        }

#pragma unroll
    for (int m = 0; m < 6; ++m) {
        const int qrow = m0 + m * 16 + quad * 4;
#pragma unroll
        for (int d2 = 0; d2 < 2; ++d2) {
            const int d = d2 * 16 + q15;
#pragma unroll
            for (int r = 0; r < 4; ++r) {
                const size_t idx = hb + (size_t)(qrow + r) * D_DIM + d;
                const float g = bf2f(gob[idx]);
                gob[idx] = f2bf(Oacc[m][d2][r] * inv[m][r] * g);
            }
        }
    }
}

// ---------------------------------------------------------------------------
// out: MFMA GEMM.  grid = NPOS/128 = 1152, block = 256.  (r6 staged verbatim)
// ---------------------------------------------------------------------------
__global__ __launch_bounds__(256) void out_kernel(
    const unsigned short* __restrict__ og, const unsigned short* __restrict__ WtO,
    const float* __restrict__ bo, float* __restrict__ out)
{
    __shared__ unsigned short At[128 * 128];
    __shared__ unsigned short Bt[128 * 128];

    const int t = threadIdx.x;
    const int pos0 = blockIdx.x * 128;
    const int lane = t & 63, wave = t >> 6;
    const int q15 = lane & 15, quad = lane >> 4;

    {
        const int r = t >> 1, half = t & 1;
        const int pos = pos0 + r;
        const int i = pos / J_DIM, j = pos - (pos / J_DIM) * J_DIM;
#pragma unroll
        for (int u = 0; u < 8; ++u) {
            const int k0 = half * 64 + u * 8;
            const int hh = k0 >> 5, d0 = k0 & 31;
            const int4 v = *(const int4*)(og + (((size_t)i * H_DIM + hh) * J_DIM + j) * D_DIM + d0);
            const int c = half * 8 + u;
            *(int4*)&At[r * 128 + ((c ^ (r & 7)) * 8)] = v;
        }
        const unsigned short* src = WtO + r * 128 + half * 64;
#pragma unroll
        for (int u = 0; u < 8; ++u) {
            const int c = half * 8 + u;
            *(int4*)&Bt[r * 128 + ((c ^ (r & 7)) * 8)] = *(const int4*)(src + u * 8);
        }
    }
    __syncthreads();

    const int m0 = wave * 32;
    f32x4 acc[2][8];
#pragma unroll
    for (int mt = 0; mt < 2; ++mt)
#pragma unroll
        for (int nt = 0; nt < 8; ++nt) acc[mt][nt] = (f32x4){0.f, 0.f, 0.f, 0.f};

#pragma unroll
    for (int kk = 0; kk < 4; ++kk) {
        const int sw = ((kk * 4 + quad) ^ (q15 & 7)) * 8;
        const bf16x8 a0 = *(const bf16x8*)&At[(m0 + q15) * 128 + sw];
        const bf16x8 a1 = *(const bf16x8*)&At[(m0 + 16 + q15) * 128 + sw];
#pragma unroll
        for (int nt = 0; nt < 8; ++nt) {
            const bf16x8 b = *(const bf16x8*)&Bt[(nt * 16 + q15) * 128 + sw];
            acc[0][nt] = __builtin_amdgcn_mfma_f32_16x16x32_bf16(a0, b, acc[0][nt], 0, 0, 0);
            acc[1][nt] = __builtin_amdgcn_mfma_f32_16x16x32_bf16(a1, b, acc[1][nt], 0, 0, 0);
        }
    }

#pragma unroll
    for (int mt = 0; mt < 2; ++mt)
#pragma unroll
        for (int nt = 0; nt < 8; ++nt) {
            const float bov = bo[nt * 16 + q15];
#pragma unroll
            for (int reg = 0; reg < 4; ++reg) {
                const int pos = pos0 + m0 + mt * 16 + quad * 4 + reg;
                out[(size_t)pos * C_DIM + nt * 16 + q15] = acc[mt][nt][reg] + bov;
            }
        }
}

// ---------------------------------------------------------------------------
extern "C" void kernel_launch(void* const* d_in, const int* in_sizes, int n_in,
                              void* d_out, int out_size, void* d_ws, size_t ws_size,
                              hipStream_t stream)
{
    const float* x     = (const float*)d_in[0];
    const float* mask  = (const float*)d_in[1];
    const float* ln_g  = (const float*)d_in[2];
    const float* ln_b  = (const float*)d_in[3];
    const float* w_tri = (const float*)d_in[4];
    const float* wq    = (const float*)d_in[5];
    const float* wk    = (const float*)d_in[6];
    const float* wv    = (const float*)d_in[7];
    const float* wg    = (const float*)d_in[8];
    const float* bg    = (const float*)d_in[9];
    const float* wo    = (const float*)d_in[10];
    const float* bo    = (const float*)d_in[11];
    float* out = (float*)d_out;
    char* ws = (char*)d_ws;

    const size_t NE = (size_t)NPOS * 128;   // elements per [I,H,J,D] buffer
    unsigned short* qb = (unsigned short*)ws;                     // bf16 36 MiB
    unsigned short* kb = (unsigned short*)(ws + NE * 2);
    unsigned short* vb = (unsigned short*)(ws + NE * 4);
    unsigned short* gb = (unsigned short*)(ws + NE * 6);          // g -> og
    float*         tri = (float*)(ws + NE * 8);                   // [H][J][I]
    unsigned short* Wt = (unsigned short*)(ws + NE * 8 + (size_t)NPOS * 4 * 4);
    unsigned short* xn = Wt + 5 * 16384;                          // bf16 [pos][c]

    prep_kernel<<<5, 256, 0, stream>>>(wq, wk, wv, wg, wo, Wt);
    ln_kernel<<<NPOS / 64, 256, 0, stream>>>(x, ln_g, ln_b, w_tri, xn, tri);
    pgemm_kernel<<<NPOS / 128, 256, 0, stream>>>(xn, Wt, bg, qb, kb, vb, gb);
    attn_kernel<<<I_DIM * H_DIM, 256, 0, stream>>>(qb, kb, vb, gb, tri, mask);
    out_kernel<<<NPOS / 128, 256, 0, stream>>>(gb, Wt + 4 * 16384, bo, out);
}

// Round 11
// 473.308 us; speedup vs baseline: 1.1170x; 1.0059x over previous
//
#include <hip/hip_runtime.h>
#include <math.h>

// TriangleAttention: B=1, I=J=384, C=128, H=4, D=32, fp32 in/out.
//
// Round-11: attn stages the ENTIRE K/V panel (384x32 each, 48KB) once --
// one HBM round-trip + one barrier per block, then the full 6-kt loop is
// barrier-free (K/V read-only, P wave-local). Same bytes as r6 (r8's 4x
// re-read mistake avoided). LDS 68.4KB -> 2 blocks/CU = 8 waves, >= the
// measured-effective 7.4 waves, so no real concurrency lost.
// Compute loops byte-identical to r6. Everything else r10 verbatim (476us).
//
// prep:    transpose 5 weight mats to bf16 [n][k] B-frag layout; Q_SCALE in wq.
// ln:      LN (fp32) + tri bias; writes xn (bf16 [pos][c], coalesced) and tri
//          [h][j][i] directly (scattered 4B, proven-neutral).
// pgemm:   per 128-row tile: stage At from xn; 4x { stage Bt from L2-hot Wt;
//          MFMA 16x16x32; epilogue C->Bt(bf16) -> coalesced global }.
// attn:    see above.  LDS = 24.6K (K) + 24.8K (Vt, stride 388 == same bank
//          profile as 68) + 17.4K (P) + 1.5K (Mb) = 68352 B.
// out:     MFMA GEMM og x woT, staged Bt.
//
// LDS swizzle (pgemm/out): row-major [row][128 bf16], chunk at (c^(row&7)).

#define I_DIM 384
#define J_DIM 384
#define C_DIM 128
#define H_DIM 4
#define D_DIM 32
#define NPOS (I_DIM * J_DIM)
#define Q_SCALE 0.17677669529663687f  // 1/sqrt(32)

typedef __attribute__((ext_vector_type(8))) short bf16x8;
typedef __attribute__((ext_vector_type(4))) float f32x4;

__device__ __forceinline__ float sigmoidf_(float v) {
    return 1.0f / (1.0f + __expf(-v));
}
__device__ __forceinline__ unsigned short f2bf(float f) {
    union { float f; unsigned u; } x; x.f = f;
    unsigned u = x.u;
    u += 0x7fffu + ((u >> 16) & 1u);
    return (unsigned short)(u >> 16);
}
__device__ __forceinline__ float bf2f(unsigned short v) {
    union { unsigned u; float f; } x; x.u = ((unsigned)v) << 16;
    return x.f;
}

// ---------------------------------------------------------------------------
// prep: Wt[mat][n][k] = W[k*128+n] (bf16), mat 0..4 = wq,wk,wv,wg,wo.
// ---------------------------------------------------------------------------
__global__ __launch_bounds__(256) void prep_kernel(
    const float* __restrict__ wq, const float* __restrict__ wk,
    const float* __restrict__ wv, const float* __restrict__ wg,
    const float* __restrict__ wo, unsigned short* __restrict__ Wt)
{
    const int mat = blockIdx.x;
    const float* W = (mat == 0) ? wq : (mat == 1) ? wk : (mat == 2) ? wv
                    : (mat == 3) ? wg : wo;
    const float scale = (mat == 0) ? Q_SCALE : 1.0f;
    const int t = threadIdx.x;
    const int n = t >> 1, c0 = (t & 1) * 64;
#pragma unroll
    for (int u = 0; u < 8; ++u) {
        unsigned pk[4];
#pragma unroll
        for (int w = 0; w < 4; ++w) {
            const unsigned short a = f2bf(W[(size_t)(c0 + u * 8 + w * 2 + 0) * 128 + n] * scale);
            const unsigned short b = f2bf(W[(size_t)(c0 + u * 8 + w * 2 + 1) * 128 + n] * scale);
            pk[w] = (unsigned)a | ((unsigned)b << 16);
        }
        int4 q; q.x = pk[0]; q.y = pk[1]; q.z = pk[2]; q.w = pk[3];
        *(int4*)(Wt + (size_t)mat * 16384 + n * 128 + c0 + u * 8) = q;
    }
}

// ---------------------------------------------------------------------------
// ln: pure streaming LayerNorm + tri bias.  grid = NPOS/64 = 2304, block 256.
// 4 threads per row (q = 32-ch slice).  Writes xn bf16 [pos][c] (coalesced)
// + tri [h][j][i] directly (scattered 4B, proven-neutral).
// ---------------------------------------------------------------------------
__global__ __launch_bounds__(256) void ln_kernel(
    const float* __restrict__ x, const float* __restrict__ ln_g,
    const float* __restrict__ ln_b, const float* __restrict__ w_tri,
    unsigned short* __restrict__ xn, float* __restrict__ tri)
{
    const int t = threadIdx.x;
    const int g = t >> 2, q = t & 3;
    const int pos = blockIdx.x * 64 + g;
    const float* xrow = x + (size_t)pos * C_DIM + q * 32;

    float xv[32];
    float s = 0.f, ss = 0.f;
#pragma unroll
    for (int u = 0; u < 8; ++u) {
        float4 v4 = ((const float4*)xrow)[u];
        xv[u * 4 + 0] = v4.x; xv[u * 4 + 1] = v4.y;
        xv[u * 4 + 2] = v4.z; xv[u * 4 + 3] = v4.w;
        s  += v4.x + v4.y + v4.z + v4.w;
        ss += v4.x * v4.x + v4.y * v4.y + v4.z * v4.z + v4.w * v4.w;
    }
    s  += __shfl_xor(s, 1);  s  += __shfl_xor(s, 2);
    ss += __shfl_xor(ss, 1); ss += __shfl_xor(ss, 2);
    const float mu  = s * (1.0f / 128.0f);
    const float var = ss * (1.0f / 128.0f) - mu * mu;
    const float rstd = rsqrtf(var + 1e-5f);

    float ptri[4] = {0.f, 0.f, 0.f, 0.f};
    unsigned short* xdst = xn + (size_t)pos * C_DIM + q * 32;
#pragma unroll
    for (int u2 = 0; u2 < 4; ++u2) {   // chunk of 8 channels
        const int cb = q * 32 + u2 * 8;
        const float4 g0 = *(const float4*)(ln_g + cb);
        const float4 g1 = *(const float4*)(ln_g + cb + 4);
        const float4 b0 = *(const float4*)(ln_b + cb);
        const float4 b1 = *(const float4*)(ln_b + cb + 4);
        float xn8[8];
        xn8[0] = (xv[u2 * 8 + 0] - mu) * rstd * g0.x + b0.x;
        xn8[1] = (xv[u2 * 8 + 1] - mu) * rstd * g0.y + b0.y;
        xn8[2] = (xv[u2 * 8 + 2] - mu) * rstd * g0.z + b0.z;
        xn8[3] = (xv[u2 * 8 + 3] - mu) * rstd * g0.w + b0.w;
        xn8[4] = (xv[u2 * 8 + 4] - mu) * rstd * g1.x + b1.x;
        xn8[5] = (xv[u2 * 8 + 5] - mu) * rstd * g1.y + b1.y;
        xn8[6] = (xv[u2 * 8 + 6] - mu) * rstd * g1.z + b1.z;
        xn8[7] = (xv[u2 * 8 + 7] - mu) * rstd * g1.w + b1.w;
#pragma unroll
        for (int w = 0; w < 8; ++w) {
            const float4 wt = ((const float4*)w_tri)[cb + w];
            ptri[0] += xn8[w] * wt.x; ptri[1] += xn8[w] * wt.y;
            ptri[2] += xn8[w] * wt.z; ptri[3] += xn8[w] * wt.w;
        }
        unsigned pk[4];
#pragma unroll
        for (int w = 0; w < 4; ++w)
            pk[w] = (unsigned)f2bf(xn8[w * 2]) | ((unsigned)f2bf(xn8[w * 2 + 1]) << 16);
        int4 q4; q4.x = pk[0]; q4.y = pk[1]; q4.z = pk[2]; q4.w = pk[3];
        *(int4*)(xdst + u2 * 8) = q4;
    }
#pragma unroll
    for (int hh = 0; hh < 4; ++hh) {
        ptri[hh] += __shfl_xor(ptri[hh], 1);
        ptri[hh] += __shfl_xor(ptri[hh], 2);
    }
    const int i = pos / J_DIM, j = pos - (pos / J_DIM) * J_DIM;
    tri[((size_t)q * J_DIM + j) * I_DIM + i] = ptri[q];
}

// ---------------------------------------------------------------------------
// pgemm: 4 MFMA GEMMs from xn.  grid = NPOS/128 = 1152, block = 256.
// LDS 64KB (At + Bt, Ct reuses Bt) -> 2 blocks/CU.  (r6 verbatim)
// ---------------------------------------------------------------------------
__global__ __launch_bounds__(256) void pgemm_kernel(
    const unsigned short* __restrict__ xn, const unsigned short* __restrict__ Wt,
    const float* __restrict__ bg,
    unsigned short* __restrict__ qb, unsigned short* __restrict__ kb,
    unsigned short* __restrict__ vb, unsigned short* __restrict__ gb)
{
    __shared__ unsigned short At[128 * 128];
    __shared__ unsigned short Bt[128 * 128];

    const int t = threadIdx.x;
    const int pos0 = blockIdx.x * 128;
    const int lane = t & 63, wave = t >> 6;
    const int q15 = lane & 15, quad = lane >> 4;

    // ---- stage At (swizzled) from xn ----
    {
        const int r = t >> 1, half = t & 1;
        const unsigned short* src = xn + (size_t)(pos0 + r) * C_DIM + half * 64;
#pragma unroll
        for (int u = 0; u < 8; ++u) {
            const int c = half * 8 + u;
            *(int4*)&At[r * 128 + ((c ^ (r & 7)) * 8)] = *(const int4*)(src + u * 8);
        }
    }

    const int m0 = wave * 32;
    for (int mat = 0; mat < 4; ++mat) {
        __syncthreads();
        // ---- stage B-tile (swizzled) ----
        {
            const int rn = t >> 1, half = t & 1;
            const unsigned short* src = Wt + (size_t)mat * 16384 + rn * 128 + half * 64;
#pragma unroll
            for (int u = 0; u < 8; ++u) {
                const int c = half * 8 + u;
                *(int4*)&Bt[rn * 128 + ((c ^ (rn & 7)) * 8)] = *(const int4*)(src + u * 8);
            }
        }
        __syncthreads();

        f32x4 acc[2][8];
#pragma unroll
        for (int mt = 0; mt < 2; ++mt)
#pragma unroll
            for (int nt = 0; nt < 8; ++nt) acc[mt][nt] = (f32x4){0.f, 0.f, 0.f, 0.f};

#pragma unroll
        for (int kk = 0; kk < 4; ++kk) {
            // all hot rows are ≡ q15 (mod 16) -> row&7 == q15&7 -> common swizzle
            const int sw = ((kk * 4 + quad) ^ (q15 & 7)) * 8;
            const bf16x8 a0 = *(const bf16x8*)&At[(m0 + q15) * 128 + sw];
            const bf16x8 a1 = *(const bf16x8*)&At[(m0 + 16 + q15) * 128 + sw];
#pragma unroll
            for (int nt = 0; nt < 8; ++nt) {
                const bf16x8 b = *(const bf16x8*)&Bt[(nt * 16 + q15) * 128 + sw];
                acc[0][nt] = __builtin_amdgcn_mfma_f32_16x16x32_bf16(a0, b, acc[0][nt], 0, 0, 0);
                acc[1][nt] = __builtin_amdgcn_mfma_f32_16x16x32_bf16(a1, b, acc[1][nt], 0, 0, 0);
            }
        }

        // ---- epilogue: C -> Bt (bf16, swizzled) -> vectorized global ----
        __syncthreads();
#pragma unroll
        for (int mt = 0; mt < 2; ++mt)
#pragma unroll
            for (int nt = 0; nt < 8; ++nt) {
                const int col = nt * 16 + q15;
                const float bgl = (mat == 3) ? bg[col] : 0.f;
#pragma unroll
                for (int reg = 0; reg < 4; ++reg) {
                    float v = acc[mt][nt][reg];
                    if (mat == 3) v = sigmoidf_(v + bgl);
                    const int row = m0 + mt * 16 + quad * 4 + reg;
                    Bt[row * 128 + (((col >> 3) ^ (row & 7)) * 8) + (col & 7)] = f2bf(v);
                }
            }
        __syncthreads();
        {
            unsigned short* O = (mat == 0) ? qb : (mat == 1) ? kb : (mat == 2) ? vb : gb;
#pragma unroll
            for (int sgm = 0; sgm < 2; ++sgm) {
                const int ch = t + sgm * 256;       // 512 chunks = 128 rows x 4 heads
                const int r = ch >> 2, hh = ch & 3;
                const int pos = pos0 + r;
                const int i = pos / J_DIM, j = pos - (pos / J_DIM) * J_DIM;
                unsigned short* dst = O + (((size_t)i * H_DIM + hh) * J_DIM + j) * D_DIM;
#pragma unroll
                for (int w = 0; w < 4; ++w) {
                    const int c = hh * 4 + w;
                    *(int4*)(dst + w * 8) = *(const int4*)&Bt[r * 128 + ((c ^ (r & 7)) * 8)];
                }
            }
        }
    }
}

// ---------------------------------------------------------------------------
// attn: MFMA flash attention.  grid = I*H = 1536, block = 256 (4 waves).
// Full K/V panel (384x32 each) staged ONCE -> one HBM round-trip + one
// barrier; the 6-kt loop is barrier-free (K/V read-only, P wave-local).
// Compute loops byte-identical to r6 (kt tile in 3 passes of 2 m-tiles).
// LDS = 24576 (K) + 24832 (Vt [32][388]) + 17408 (P) + 1536 (Mb) = 68352 B
// -> 2 blocks/CU = 8 waves (measured-effective concurrency was ~7.4).
// ---------------------------------------------------------------------------
#define VSTR 388

__global__ __launch_bounds__(256) void attn_kernel(
    const unsigned short* __restrict__ qb, const unsigned short* __restrict__ kb,
    const unsigned short* __restrict__ vb, unsigned short* gob,
    const float* __restrict__ triT, const float* __restrict__ mask)
{
    __shared__ unsigned short Klds[J_DIM * 32];
    __shared__ unsigned short Vt[32 * VSTR];
    __shared__ unsigned short Plds[4][32 * 68];
    __shared__ float Mb[J_DIM];

    const int t = threadIdx.x;
    const int lane = t & 63, wave = t >> 6;
    const int q15 = lane & 15, quad = lane >> 4;
    const int i = blockIdx.x >> 2, h = blockIdx.x & 3;
    const size_t hb = (size_t)(i * H_DIM + h) * (J_DIM * D_DIM);
    const int m0 = wave * 96;

    for (int idx = t; idx < J_DIM; idx += 256)
        Mb[idx] = 1.0e9f * (mask[i * J_DIM + idx] - 1.0f);

    // ---- one-shot K/V panel staging: 12 int4 loads/thread, all in flight ----
    {
#pragma unroll
        for (int s6 = 0; s6 < 6; ++s6) {
            const int idx = s6 * 256 + t;            // 1536 chunks = 384 rows x 4
            const int row = idx >> 2, part = idx & 3;
            const size_t gsrc = hb + (size_t)row * D_DIM + part * 8;
            *(int4*)&Klds[row * 32 + part * 8] = *(const int4*)(kb + gsrc);
            int4 vv = *(const int4*)(vb + gsrc);
            const unsigned short* vs = (const unsigned short*)&vv;
#pragma unroll
            for (int u = 0; u < 8; ++u)
                Vt[(part * 8 + u) * VSTR + row] = vs[u];
        }
    }
    __syncthreads();   // the only block barrier

    bf16x8 qf[6];
#pragma unroll
    for (int m = 0; m < 6; ++m)
        qf[m] = *(const bf16x8*)(qb + hb + (size_t)(m0 + m * 16 + q15) * D_DIM + quad * 8);

    f32x4 Oacc[6][2];
    float sums[6][4];
#pragma unroll
    for (int m = 0; m < 6; ++m) {
#pragma unroll
        for (int d2 = 0; d2 < 2; ++d2) Oacc[m][d2] = (f32x4){0.f, 0.f, 0.f, 0.f};
#pragma unroll
        for (int r = 0; r < 4; ++r) sums[m][r] = 0.f;
    }

    unsigned short* Pw = Plds[wave];
    const float* triH = triT + (size_t)h * J_DIM * I_DIM;

    for (int kt = 0; kt < 6; ++kt) {
        // V fragments for this kt (reused by all 3 passes)
        bf16x8 vf[2][2];
#pragma unroll
        for (int ks = 0; ks < 2; ++ks)
#pragma unroll
            for (int d2 = 0; d2 < 2; ++d2)
                vf[ks][d2] = *(const bf16x8*)&Vt[(d2 * 16 + q15) * VSTR + kt * 64 + ks * 32 + quad * 8];

#pragma unroll
        for (int pass = 0; pass < 3; ++pass) {
            const int mbase = pass * 2;

            // ---- QK^T + exp for 2 m-tiles (nt-outer, kf loaded once/nt) ----
#pragma unroll
            for (int nt = 0; nt < 4; ++nt) {
                const bf16x8 kf = *(const bf16x8*)&Klds[(kt * 64 + nt * 16 + q15) * 32 + quad * 8];
                const float mb = Mb[kt * 64 + nt * 16 + q15];
                const float* tcol = triH + (size_t)(kt * 64 + nt * 16 + q15) * I_DIM;
#pragma unroll
                for (int mm = 0; mm < 2; ++mm) {
                    const int m = mbase + mm;
                    const float4 tb = *(const float4*)(tcol + m0 + m * 16 + quad * 4);
                    f32x4 s = {0.f, 0.f, 0.f, 0.f};
                    s = __builtin_amdgcn_mfma_f32_16x16x32_bf16(qf[m], kf, s, 0, 0, 0);
                    const float p0 = __expf(s[0] + mb + tb.x);
                    const float p1 = __expf(s[1] + mb + tb.y);
                    const float p2 = __expf(s[2] + mb + tb.z);
                    const float p3 = __expf(s[3] + mb + tb.w);
                    sums[m][0] += p0; sums[m][1] += p1;
                    sums[m][2] += p2; sums[m][3] += p3;
                    const int row = mm * 16 + quad * 4;
                    const int col = nt * 16 + q15;
                    Pw[(row + 0) * 68 + col] = f2bf(p0);
                    Pw[(row + 1) * 68 + col] = f2bf(p1);
                    Pw[(row + 2) * 68 + col] = f2bf(p2);
                    Pw[(row + 3) * 68 + col] = f2bf(p3);
                }
            }

            // ---- PV for those 2 m-tiles (wave-local P, no barrier needed) ----
#pragma unroll
            for (int mm = 0; mm < 2; ++mm) {
                const int m = mbase + mm;
#pragma unroll
                for (int ks = 0; ks < 2; ++ks) {
                    const bf16x8 af = *(const bf16x8*)&Pw[(mm * 16 + q15) * 68 + ks * 32 + quad * 8];
                    Oacc[m][0] = __builtin_amdgcn_mfma_f32_16x16x32_bf16(af, vf[ks][0], Oacc[m][0], 0, 0, 0);
                    Oacc[m][1] = __builtin_amdgcn_mfma_f32_16x16x32_bf16(af, vf[ks][1], Oacc[m][1], 0, 0, 0);
                }
            }
        }
    }

    float inv[6][4];
#pragma unroll
    for (int m = 0; m < 6; ++m)
#pragma unroll
        for (int r = 0; r < 4; ++r) {
            float s0 = sums[m][r];
            s0 += __shfl_xor(s0, 1); s0 += __shfl_xor(s0, 2);
            s0 += __shfl_xor(s0, 4); s0 += __shfl_xor(s0, 8);
            inv[m][r] = 1.0f / s0;
        }

#pragma unroll
    for (int m = 0; m < 6; ++m) {
        const int qrow = m0 + m * 16 + quad * 4;
#pragma unroll
        for (int d2 = 0; d2 < 2; ++d2) {
            const int d = d2 * 16 + q15;
#pragma unroll
            for (int r = 0; r < 4; ++r) {
                const size_t idx = hb + (size_t)(qrow + r) * D_DIM + d;
                const float g = bf2f(gob[idx]);
                gob[idx] = f2bf(Oacc[m][d2][r] * inv[m][r] * g);
            }
        }
    }
}

// ---------------------------------------------------------------------------
// out: MFMA GEMM.  grid = NPOS/128 = 1152, block = 256.  (r6 staged verbatim)
// ---------------------------------------------------------------------------
__global__ __launch_bounds__(256) void out_kernel(
    const unsigned short* __restrict__ og, const unsigned short* __restrict__ WtO,
    const float* __restrict__ bo, float* __restrict__ out)
{
    __shared__ unsigned short At[128 * 128];
    __shared__ unsigned short Bt[128 * 128];

    const int t = threadIdx.x;
    const int pos0 = blockIdx.x * 128;
    const int lane = t & 63, wave = t >> 6;
    const int q15 = lane & 15, quad = lane >> 4;

    {
        const int r = t >> 1, half = t & 1;
        const int pos = pos0 + r;
        const int i = pos / J_DIM, j = pos - (pos / J_DIM) * J_DIM;
#pragma unroll
        for (int u = 0; u < 8; ++u) {
            const int k0 = half * 64 + u * 8;
            const int hh = k0 >> 5, d0 = k0 & 31;
            const int4 v = *(const int4*)(og + (((size_t)i * H_DIM + hh) * J_DIM + j) * D_DIM + d0);
            const int c = half * 8 + u;
            *(int4*)&At[r * 128 + ((c ^ (r & 7)) * 8)] = v;
        }
        const unsigned short* src = WtO + r * 128 + half * 64;
#pragma unroll
        for (int u = 0; u < 8; ++u) {
            const int c = half * 8 + u;
            *(int4*)&Bt[r * 128 + ((c ^ (r & 7)) * 8)] = *(const int4*)(src + u * 8);
        }
    }
    __syncthreads();

    const int m0 = wave * 32;
    f32x4 acc[2][8];
#pragma unroll
    for (int mt = 0; mt < 2; ++mt)
#pragma unroll
        for (int nt = 0; nt < 8; ++nt) acc[mt][nt] = (f32x4){0.f, 0.f, 0.f, 0.f};

#pragma unroll
    for (int kk = 0; kk < 4; ++kk) {
        const int sw = ((kk * 4 + quad) ^ (q15 & 7)) * 8;
        const bf16x8 a0 = *(const bf16x8*)&At[(m0 + q15) * 128 + sw];
        const bf16x8 a1 = *(const bf16x8*)&At[(m0 + 16 + q15) * 128 + sw];
#pragma unroll
        for (int nt = 0; nt < 8; ++nt) {
            const bf16x8 b = *(const bf16x8*)&Bt[(nt * 16 + q15) * 128 + sw];
            acc[0][nt] = __builtin_amdgcn_mfma_f32_16x16x32_bf16(a0, b, acc[0][nt], 0, 0, 0);
            acc[1][nt] = __builtin_amdgcn_mfma_f32_16x16x32_bf16(a1, b, acc[1][nt], 0, 0, 0);
        }
    }

#pragma unroll
    for (int mt = 0; mt < 2; ++mt)
#pragma unroll
        for (int nt = 0; nt < 8; ++nt) {
            const float bov = bo[nt * 16 + q15];
#pragma unroll
            for (int reg = 0; reg < 4; ++reg) {
                const int pos = pos0 + m0 + mt * 16 + quad * 4 + reg;
                out[(size_t)pos * C_DIM + nt * 16 + q15] = acc[mt][nt][reg] + bov;
            }
        }
}

// ---------------------------------------------------------------------------
extern "C" void kernel_launch(void* const* d_in, const int* in_sizes, int n_in,
                              void* d_out, int out_size, void* d_ws, size_t ws_size,
                              hipStream_t stream)
{
    const float* x     = (const float*)d_in[0];
    const float* mask  = (const float*)d_in[1];
    const float* ln_g  = (const float*)d_in[2];
    const float* ln_b  = (const float*)d_in[3];
    const float* w_tri = (const float*)d_in[4];
    const float* wq    = (const float*)d_in[5];
    const float* wk    = (const float*)d_in[6];
    const float* wv    = (const float*)d_in[7];
    const float* wg    = (const float*)d_in[8];
    const float* bg    = (const float*)d_in[9];
    const float* wo    = (const float*)d_in[10];
    const float* bo    = (const float*)d_in[11];
    float* out = (float*)d_out;
    char* ws = (char*)d_ws;

    const size_t NE = (size_t)NPOS * 128;   // elements per [I,H,J,D] buffer
    unsigned short* qb = (unsigned short*)ws;                     // bf16 36 MiB
    unsigned short* kb = (unsigned short*)(ws + NE * 2);
    unsigned short* vb = (unsigned short*)(ws + NE * 4);
    unsigned short* gb = (unsigned short*)(ws + NE * 6);          // g -> og
    float*         tri = (float*)(ws + NE * 8);                   // [H][J][I]
    unsigned short* Wt = (unsigned short*)(ws + NE * 8 + (size_t)NPOS * 4 * 4);
    unsigned short* xn = Wt + 5 * 16384;                          // bf16 [pos][c]

    prep_kernel<<<5, 256, 0, stream>>>(wq, wk, wv, wg, wo, Wt);
    ln_kernel<<<NPOS / 64, 256, 0, stream>>>(x, ln_g, ln_b, w_tri, xn, tri);
    pgemm_kernel<<<NPOS / 128, 256, 0, stream>>>(xn, Wt, bg, qb, kb, vb, gb);
    attn_kernel<<<I_DIM * H_DIM, 256, 0, stream>>>(qb, kb, vb, gb, tri, mask);
    out_kernel<<<NPOS / 128, 256, 0, stream>>>(gb, Wt + 4 * 16384, bo, out);
}

// Round 12
// 471.598 us; speedup vs baseline: 1.1210x; 1.0036x over previous
//
#include <hip/hip_runtime.h>
#include <math.h>

// TriangleAttention: B=1, I=J=384, C=128, H=4, D=32, fp32 in/out.
//
// Round-12: attn K/V panel staged in TWO HALVES of 192 rows (was whole panel)
// -> LDS 68.6KB -> 43.9KB -> 3 blocks/CU = 12 waves (+50% concurrency for
// latency hiding of tri L2 reads + exp chains, the r11-identified stall).
// Costs one mid-kernel re-stage (2 extra barriers; r11 proved a full-panel
// stage is ~1-2us). Compute loops byte-identical to r6/r11.
// Everything else r11 verbatim (473us config).
//
// prep:    transpose 5 weight mats to bf16 [n][k] B-frag layout; Q_SCALE in wq.
// ln:      LN (fp32) + tri bias; writes xn (bf16 [pos][c], coalesced) and tri
//          [h][j][i] directly (scattered 4B, proven-neutral).
// pgemm:   per 128-row tile: stage At from xn; 4x { stage Bt from L2-hot Wt;
//          MFMA 16x16x32; epilogue C->Bt(bf16) -> coalesced global }.
// attn:    see above.  LDS = 12288 (K half) + 12672 (Vt [32][198]) +
//          17408 (P) + 1536 (Mb) = 43904 B -> 3 blocks/CU.
// out:     MFMA GEMM og x woT, staged Bt.
//
// LDS swizzle (pgemm/out): row-major [row][128 bf16], chunk at (c^(row&7)).

#define I_DIM 384
#define J_DIM 384
#define C_DIM 128
#define H_DIM 4
#define D_DIM 32
#define NPOS (I_DIM * J_DIM)
#define Q_SCALE 0.17677669529663687f  // 1/sqrt(32)

typedef __attribute__((ext_vector_type(8))) short bf16x8;
typedef __attribute__((ext_vector_type(4))) float f32x4;

__device__ __forceinline__ float sigmoidf_(float v) {
    return 1.0f / (1.0f + __expf(-v));
}
__device__ __forceinline__ unsigned short f2bf(float f) {
    union { float f; unsigned u; } x; x.f = f;
    unsigned u = x.u;
    u += 0x7fffu + ((u >> 16) & 1u);
    return (unsigned short)(u >> 16);
}
__device__ __forceinline__ float bf2f(unsigned short v) {
    union { unsigned u; float f; } x; x.u = ((unsigned)v) << 16;
    return x.f;
}

// ---------------------------------------------------------------------------
// prep: Wt[mat][n][k] = W[k*128+n] (bf16), mat 0..4 = wq,wk,wv,wg,wo.
// ---------------------------------------------------------------------------
__global__ __launch_bounds__(256) void prep_kernel(
    const float* __restrict__ wq, const float* __restrict__ wk,
    const float* __restrict__ wv, const float* __restrict__ wg,
    const float* __restrict__ wo, unsigned short* __restrict__ Wt)
{
    const int mat = blockIdx.x;
    const float* W = (mat == 0) ? wq : (mat == 1) ? wk : (mat == 2) ? wv
                    : (mat == 3) ? wg : wo;
    const float scale = (mat == 0) ? Q_SCALE : 1.0f;
    const int t = threadIdx.x;
    const int n = t >> 1, c0 = (t & 1) * 64;
#pragma unroll
    for (int u = 0; u < 8; ++u) {
        unsigned pk[4];
#pragma unroll
        for (int w = 0; w < 4; ++w) {
            const unsigned short a = f2bf(W[(size_t)(c0 + u * 8 + w * 2 + 0) * 128 + n] * scale);
            const unsigned short b = f2bf(W[(size_t)(c0 + u * 8 + w * 2 + 1) * 128 + n] * scale);
            pk[w] = (unsigned)a | ((unsigned)b << 16);
        }
        int4 q; q.x = pk[0]; q.y = pk[1]; q.z = pk[2]; q.w = pk[3];
        *(int4*)(Wt + (size_t)mat * 16384 + n * 128 + c0 + u * 8) = q;
    }
}

// ---------------------------------------------------------------------------
// ln: pure streaming LayerNorm + tri bias.  grid = NPOS/64 = 2304, block 256.
// 4 threads per row (q = 32-ch slice).  Writes xn bf16 [pos][c] (coalesced)
// + tri [h][j][i] directly (scattered 4B, proven-neutral).
// ---------------------------------------------------------------------------
__global__ __launch_bounds__(256) void ln_kernel(
    const float* __restrict__ x, const float* __restrict__ ln_g,
    const float* __restrict__ ln_b, const float* __restrict__ w_tri,
    unsigned short* __restrict__ xn, float* __restrict__ tri)
{
    const int t = threadIdx.x;
    const int g = t >> 2, q = t & 3;
    const int pos = blockIdx.x * 64 + g;
    const float* xrow = x + (size_t)pos * C_DIM + q * 32;

    float xv[32];
    float s = 0.f, ss = 0.f;
#pragma unroll
    for (int u = 0; u < 8; ++u) {
        float4 v4 = ((const float4*)xrow)[u];
        xv[u * 4 + 0] = v4.x; xv[u * 4 + 1] = v4.y;
        xv[u * 4 + 2] = v4.z; xv[u * 4 + 3] = v4.w;
        s  += v4.x + v4.y + v4.z + v4.w;
        ss += v4.x * v4.x + v4.y * v4.y + v4.z * v4.z + v4.w * v4.w;
    }
    s  += __shfl_xor(s, 1);  s  += __shfl_xor(s, 2);
    ss += __shfl_xor(ss, 1); ss += __shfl_xor(ss, 2);
    const float mu  = s * (1.0f / 128.0f);
    const float var = ss * (1.0f / 128.0f) - mu * mu;
    const float rstd = rsqrtf(var + 1e-5f);

    float ptri[4] = {0.f, 0.f, 0.f, 0.f};
    unsigned short* xdst = xn + (size_t)pos * C_DIM + q * 32;
#pragma unroll
    for (int u2 = 0; u2 < 4; ++u2) {   // chunk of 8 channels
        const int cb = q * 32 + u2 * 8;
        const float4 g0 = *(const float4*)(ln_g + cb);
        const float4 g1 = *(const float4*)(ln_g + cb + 4);
        const float4 b0 = *(const float4*)(ln_b + cb);
        const float4 b1 = *(const float4*)(ln_b + cb + 4);
        float xn8[8];
        xn8[0] = (xv[u2 * 8 + 0] - mu) * rstd * g0.x + b0.x;
        xn8[1] = (xv[u2 * 8 + 1] - mu) * rstd * g0.y + b0.y;
        xn8[2] = (xv[u2 * 8 + 2] - mu) * rstd * g0.z + b0.z;
        xn8[3] = (xv[u2 * 8 + 3] - mu) * rstd * g0.w + b0.w;
        xn8[4] = (xv[u2 * 8 + 4] - mu) * rstd * g1.x + b1.x;
        xn8[5] = (xv[u2 * 8 + 5] - mu) * rstd * g1.y + b1.y;
        xn8[6] = (xv[u2 * 8 + 6] - mu) * rstd * g1.z + b1.z;
        xn8[7] = (xv[u2 * 8 + 7] - mu) * rstd * g1.w + b1.w;
#pragma unroll
        for (int w = 0; w < 8; ++w) {
            const float4 wt = ((const float4*)w_tri)[cb + w];
            ptri[0] += xn8[w] * wt.x; ptri[1] += xn8[w] * wt.y;
            ptri[2] += xn8[w] * wt.z; ptri[3] += xn8[w] * wt.w;
        }
        unsigned pk[4];
#pragma unroll
        for (int w = 0; w < 4; ++w)
            pk[w] = (unsigned)f2bf(xn8[w * 2]) | ((unsigned)f2bf(xn8[w * 2 + 1]) << 16);
        int4 q4; q4.x = pk[0]; q4.y = pk[1]; q4.z = pk[2]; q4.w = pk[3];
        *(int4*)(xdst + u2 * 8) = q4;
    }
#pragma unroll
    for (int hh = 0; hh < 4; ++hh) {
        ptri[hh] += __shfl_xor(ptri[hh], 1);
        ptri[hh] += __shfl_xor(ptri[hh], 2);
    }
    const int i = pos / J_DIM, j = pos - (pos / J_DIM) * J_DIM;
    tri[((size_t)q * J_DIM + j) * I_DIM + i] = ptri[q];
}

// ---------------------------------------------------------------------------
// pgemm: 4 MFMA GEMMs from xn.  grid = NPOS/128 = 1152, block = 256.
// LDS 64KB (At + Bt, Ct reuses Bt) -> 2 blocks/CU.  (r6 verbatim)
// ---------------------------------------------------------------------------
__global__ __launch_bounds__(256) void pgemm_kernel(
    const unsigned short* __restrict__ xn, const unsigned short* __restrict__ Wt,
    const float* __restrict__ bg,
    unsigned short* __restrict__ qb, unsigned short* __restrict__ kb,
    unsigned short* __restrict__ vb, unsigned short* __restrict__ gb)
{
    __shared__ unsigned short At[128 * 128];
    __shared__ unsigned short Bt[128 * 128];

    const int t = threadIdx.x;
    const int pos0 = blockIdx.x * 128;
    const int lane = t & 63, wave = t >> 6;
    const int q15 = lane & 15, quad = lane >> 4;

    // ---- stage At (swizzled) from xn ----
    {
        const int r = t >> 1, half = t & 1;
        const unsigned short* src = xn + (size_t)(pos0 + r) * C_DIM + half * 64;
#pragma unroll
        for (int u = 0; u < 8; ++u) {
            const int c = half * 8 + u;
            *(int4*)&At[r * 128 + ((c ^ (r & 7)) * 8)] = *(const int4*)(src + u * 8);
        }
    }

    const int m0 = wave * 32;
    for (int mat = 0; mat < 4; ++mat) {
        __syncthreads();
        // ---- stage B-tile (swizzled) ----
        {
            const int rn = t >> 1, half = t & 1;
            const unsigned short* src = Wt + (size_t)mat * 16384 + rn * 128 + half * 64;
#pragma unroll
            for (int u = 0; u < 8; ++u) {
                const int c = half * 8 + u;
                *(int4*)&Bt[rn * 128 + ((c ^ (rn & 7)) * 8)] = *(const int4*)(src + u * 8);
            }
        }
        __syncthreads();

        f32x4 acc[2][8];
#pragma unroll
        for (int mt = 0; mt < 2; ++mt)
#pragma unroll
            for (int nt = 0; nt < 8; ++nt) acc[mt][nt] = (f32x4){0.f, 0.f, 0.f, 0.f};

#pragma unroll
        for (int kk = 0; kk < 4; ++kk) {
            // all hot rows are ≡ q15 (mod 16) -> row&7 == q15&7 -> common swizzle
            const int sw = ((kk * 4 + quad) ^ (q15 & 7)) * 8;
            const bf16x8 a0 = *(const bf16x8*)&At[(m0 + q15) * 128 + sw];
            const bf16x8 a1 = *(const bf16x8*)&At[(m0 + 16 + q15) * 128 + sw];
#pragma unroll
            for (int nt = 0; nt < 8; ++nt) {
                const bf16x8 b = *(const bf16x8*)&Bt[(nt * 16 + q15) * 128 + sw];
                acc[0][nt] = __builtin_amdgcn_mfma_f32_16x16x32_bf16(a0, b, acc[0][nt], 0, 0, 0);
                acc[1][nt] = __builtin_amdgcn_mfma_f32_16x16x32_bf16(a1, b, acc[1][nt], 0, 0, 0);
            }
        }

        // ---- epilogue: C -> Bt (bf16, swizzled) -> vectorized global ----
        __syncthreads();
#pragma unroll
        for (int mt = 0; mt < 2; ++mt)
#pragma unroll
            for (int nt = 0; nt < 8; ++nt) {
                const int col = nt * 16 + q15;
                const float bgl = (mat == 3) ? bg[col] : 0.f;
#pragma unroll
                for (int reg = 0; reg < 4; ++reg) {
                    float v = acc[mt][nt][reg];
                    if (mat == 3) v = sigmoidf_(v + bgl);
                    const int row = m0 + mt * 16 + quad * 4 + reg;
                    Bt[row * 128 + (((col >> 3) ^ (row & 7)) * 8) + (col & 7)] = f2bf(v);
                }
            }
        __syncthreads();
        {
            unsigned short* O = (mat == 0) ? qb : (mat == 1) ? kb : (mat == 2) ? vb : gb;
#pragma unroll
            for (int sgm = 0; sgm < 2; ++sgm) {
                const int ch = t + sgm * 256;       // 512 chunks = 128 rows x 4 heads
                const int r = ch >> 2, hh = ch & 3;
                const int pos = pos0 + r;
                const int i = pos / J_DIM, j = pos - (pos / J_DIM) * J_DIM;
                unsigned short* dst = O + (((size_t)i * H_DIM + hh) * J_DIM + j) * D_DIM;
#pragma unroll
                for (int w = 0; w < 4; ++w) {
                    const int c = hh * 4 + w;
                    *(int4*)(dst + w * 8) = *(const int4*)&Bt[r * 128 + ((c ^ (r & 7)) * 8)];
                }
            }
        }
    }
}

// ---------------------------------------------------------------------------
// attn: MFMA flash attention.  grid = I*H = 1536, block = 256 (4 waves).
// K/V staged in TWO HALVES of 192 rows; each half's 3-kt loop is barrier-free
// (K/V read-only, P wave-local).  3 barriers/block total.
// Compute loops byte-identical to r6 (kt tile in 3 passes of 2 m-tiles).
// LDS = 12288 (K) + 12672 (Vt [32][198], stride 198 = 99 dwords -> 1-way)
//     + 17408 (P) + 1536 (Mb) = 43904 B -> 3 blocks/CU = 12 waves.
// ---------------------------------------------------------------------------
#define VSTR 198

__global__ __launch_bounds__(256) void attn_kernel(
    const unsigned short* __restrict__ qb, const unsigned short* __restrict__ kb,
    const unsigned short* __restrict__ vb, unsigned short* gob,
    const float* __restrict__ triT, const float* __restrict__ mask)
{
    __shared__ unsigned short Klds[192 * 32];
    __shared__ unsigned short Vt[32 * VSTR];
    __shared__ unsigned short Plds[4][32 * 68];
    __shared__ float Mb[J_DIM];

    const int t = threadIdx.x;
    const int lane = t & 63, wave = t >> 6;
    const int q15 = lane & 15, quad = lane >> 4;
    const int i = blockIdx.x >> 2, h = blockIdx.x & 3;
    const size_t hb = (size_t)(i * H_DIM + h) * (J_DIM * D_DIM);
    const int m0 = wave * 96;

    for (int idx = t; idx < J_DIM; idx += 256)
        Mb[idx] = 1.0e9f * (mask[i * J_DIM + idx] - 1.0f);

    bf16x8 qf[6];
#pragma unroll
    for (int m = 0; m < 6; ++m)
        qf[m] = *(const bf16x8*)(qb + hb + (size_t)(m0 + m * 16 + q15) * D_DIM + quad * 8);

    f32x4 Oacc[6][2];
    float sums[6][4];
#pragma unroll
    for (int m = 0; m < 6; ++m) {
#pragma unroll
        for (int d2 = 0; d2 < 2; ++d2) Oacc[m][d2] = (f32x4){0.f, 0.f, 0.f, 0.f};
#pragma unroll
        for (int r = 0; r < 4; ++r) sums[m][r] = 0.f;
    }

    unsigned short* Pw = Plds[wave];
    const float* triH = triT + (size_t)h * J_DIM * I_DIM;

    for (int hp = 0; hp < 2; ++hp) {           // K/V panel half: rows hp*192..+192
        const int j0 = hp * 192;

        if (hp) __syncthreads();               // prior half's reads complete (WAR)
        // ---- stage 192-row half: 3 int4 loads/thread each of K and V ----
        {
#pragma unroll
            for (int s3 = 0; s3 < 3; ++s3) {
                const int idx = s3 * 256 + t;   // 768 chunks = 192 rows x 4 parts
                const int row = idx >> 2, part = idx & 3;
                const size_t gsrc = hb + (size_t)(j0 + row) * D_DIM + part * 8;
                *(int4*)&Klds[row * 32 + part * 8] = *(const int4*)(kb + gsrc);
                int4 vv = *(const int4*)(vb + gsrc);
                const unsigned short* vs = (const unsigned short*)&vv;
#pragma unroll
                for (int u = 0; u < 8; ++u)
                    Vt[(part * 8 + u) * VSTR + row] = vs[u];
            }
        }
        __syncthreads();                       // half staged (RAW)

        for (int lkt = 0; lkt < 3; ++lkt) {
            // V fragments for this kt (reused by all 3 passes)
            bf16x8 vf[2][2];
#pragma unroll
            for (int ks = 0; ks < 2; ++ks)
#pragma unroll
                for (int d2 = 0; d2 < 2; ++d2)
                    vf[ks][d2] = *(const bf16x8*)&Vt[(d2 * 16 + q15) * VSTR + lkt * 64 + ks * 32 + quad * 8];

#pragma unroll
            for (int pass = 0; pass < 3; ++pass) {
                const int mbase = pass * 2;

                // ---- QK^T + exp for 2 m-tiles (nt-outer, kf loaded once/nt) ----
#pragma unroll
                for (int nt = 0; nt < 4; ++nt) {
                    const bf16x8 kf = *(const bf16x8*)&Klds[(lkt * 64 + nt * 16 + q15) * 32 + quad * 8];
                    const int jg = j0 + lkt * 64 + nt * 16 + q15;
                    const float mb = Mb[jg];
                    const float* tcol = triH + (size_t)jg * I_DIM;
#pragma unroll
                    for (int mm = 0; mm < 2; ++mm) {
                        const int m = mbase + mm;
                        const float4 tb = *(const float4*)(tcol + m0 + m * 16 + quad * 4);
                        f32x4 s = {0.f, 0.f, 0.f, 0.f};
                        s = __builtin_amdgcn_mfma_f32_16x16x32_bf16(qf[m], kf, s, 0, 0, 0);
                        const float p0 = __expf(s[0] + mb + tb.x);
                        const float p1 = __expf(s[1] + mb + tb.y);
                        const float p2 = __expf(s[2] + mb + tb.z);
                        const float p3 = __expf(s[3] + mb + tb.w);
                        sums[m][0] += p0; sums[m][1] += p1;
                        sums[m][2] += p2; sums[m][3] += p3;
                        const int row = mm * 16 + quad * 4;
                        const int col = nt * 16 + q15;
                        Pw[(row + 0) * 68 + col] = f2bf(p0);
                        Pw[(row + 1) * 68 + col] = f2bf(p1);
                        Pw[(row + 2) * 68 + col] = f2bf(p2);
                        Pw[(row + 3) * 68 + col] = f2bf(p3);
                    }
                }

                // ---- PV for those 2 m-tiles (wave-local P, no barrier needed) ----
#pragma unroll
                for (int mm = 0; mm < 2; ++mm) {
                    const int m = mbase + mm;
#pragma unroll
                    for (int ks = 0; ks < 2; ++ks) {
                        const bf16x8 af = *(const bf16x8*)&Pw[(mm * 16 + q15) * 68 + ks * 32 + quad * 8];
                        Oacc[m][0] = __builtin_amdgcn_mfma_f32_16x16x32_bf16(af, vf[ks][0], Oacc[m][0], 0, 0, 0);
                        Oacc[m][1] = __builtin_amdgcn_mfma_f32_16x16x32_bf16(af, vf[ks][1], Oacc[m][1], 0, 0, 0);
                    }
                }
            }
        }
    }

    float inv[6][4];
#pragma unroll
    for (int m = 0; m < 6; ++m)
#pragma unroll
        for (int r = 0; r < 4; ++r) {
            float s0 = sums[m][r];
            s0 += __shfl_xor(s0, 1); s0 += __shfl_xor(s0, 2);
            s0 += __shfl_xor(s0, 4); s0 += __shfl_xor(s0, 8);
            inv[m][r] = 1.0f / s0;
        }

#pragma unroll
    for (int m = 0; m < 6; ++m) {
        const int qrow = m0 + m * 16 + quad * 4;
#pragma unroll
        for (int d2 = 0; d2 < 2; ++d2) {
            const int d = d2 * 16 + q15;
#pragma unroll
            for (int r = 0; r < 4; ++r) {
                const size_t idx = hb + (size_t)(qrow + r) * D_DIM + d;
                const float g = bf2f(gob[idx]);
                gob[idx] = f2bf(Oacc[m][d2][r] * inv[m][r] * g);
            }
        }
    }
}

// ---------------------------------------------------------------------------
// out: MFMA GEMM.  grid = NPOS/128 = 1152, block = 256.  (r6 staged verbatim)
// ---------------------------------------------------------------------------
__global__ __launch_bounds__(256) void out_kernel(
    const unsigned short* __restrict__ og, const unsigned short* __restrict__ WtO,
    const float* __restrict__ bo, float* __restrict__ out)
{
    __shared__ unsigned short At[128 * 128];
    __shared__ unsigned short Bt[128 * 128];

    const int t = threadIdx.x;
    const int pos0 = blockIdx.x * 128;
    const int lane = t & 63, wave = t >> 6;
    const int q15 = lane & 15, quad = lane >> 4;

    {
        const int r = t >> 1, half = t & 1;
        const int pos = pos0 + r;
        const int i = pos / J_DIM, j = pos - (pos / J_DIM) * J_DIM;
#pragma unroll
        for (int u = 0; u < 8; ++u) {
            const int k0 = half * 64 + u * 8;
            const int hh = k0 >> 5, d0 = k0 & 31;
            const int4 v = *(const int4*)(og + (((size_t)i * H_DIM + hh) * J_DIM + j) * D_DIM + d0);
            const int c = half * 8 + u;
            *(int4*)&At[r * 128 + ((c ^ (r & 7)) * 8)] = v;
        }
        const unsigned short* src = WtO + r * 128 + half * 64;
#pragma unroll
        for (int u = 0; u < 8; ++u) {
            const int c = half * 8 + u;
            *(int4*)&Bt[r * 128 + ((c ^ (r & 7)) * 8)] = *(const int4*)(src + u * 8);
        }
    }
    __syncthreads();

    const int m0 = wave * 32;
    f32x4 acc[2][8];
#pragma unroll
    for (int mt = 0; mt < 2; ++mt)
#pragma unroll
        for (int nt = 0; nt < 8; ++nt) acc[mt][nt] = (f32x4){0.f, 0.f, 0.f, 0.f};

#pragma unroll
    for (int kk = 0; kk < 4; ++kk) {
        const int sw = ((kk * 4 + quad) ^ (q15 & 7)) * 8;
        const bf16x8 a0 = *(const bf16x8*)&At[(m0 + q15) * 128 + sw];
        const bf16x8 a1 = *(const bf16x8*)&At[(m0 + 16 + q15) * 128 + sw];
#pragma unroll
        for (int nt = 0; nt < 8; ++nt) {
            const bf16x8 b = *(const bf16x8*)&Bt[(nt * 16 + q15) * 128 + sw];
            acc[0][nt] = __builtin_amdgcn_mfma_f32_16x16x32_bf16(a0, b, acc[0][nt], 0, 0, 0);
            acc[1][nt] = __builtin_amdgcn_mfma_f32_16x16x32_bf16(a1, b, acc[1][nt], 0, 0, 0);
        }
    }

#pragma unroll
    for (int mt = 0; mt < 2; ++mt)
#pragma unroll
        for (int nt = 0; nt < 8; ++nt) {
            const float bov = bo[nt * 16 + q15];
#pragma unroll
            for (int reg = 0; reg < 4; ++reg) {
                const int pos = pos0 + m0 + mt * 16 + quad * 4 + reg;
                out[(size_t)pos * C_DIM + nt * 16 + q15] = acc[mt][nt][reg] + bov;
            }
        }
}

// ---------------------------------------------------------------------------
extern "C" void kernel_launch(void* const* d_in, const int* in_sizes, int n_in,
                              void* d_out, int out_size, void* d_ws, size_t ws_size,
                              hipStream_t stream)
{
    const float* x     = (const float*)d_in[0];
    const float* mask  = (const float*)d_in[1];
    const float* ln_g  = (const float*)d_in[2];
    const float* ln_b  = (const float*)d_in[3];
    const float* w_tri = (const float*)d_in[4];
    const float* wq    = (const float*)d_in[5];
    const float* wk    = (const float*)d_in[6];
    const float* wv    = (const float*)d_in[7];
    const float* wg    = (const float*)d_in[8];
    const float* bg    = (const float*)d_in[9];
    const float* wo    = (const float*)d_in[10];
    const float* bo    = (const float*)d_in[11];
    float* out = (float*)d_out;
    char* ws = (char*)d_ws;

    const size_t NE = (size_t)NPOS * 128;   // elements per [I,H,J,D] buffer
    unsigned short* qb = (unsigned short*)ws;                     // bf16 36 MiB
    unsigned short* kb = (unsigned short*)(ws + NE * 2);
    unsigned short* vb = (unsigned short*)(ws + NE * 4);
    unsigned short* gb = (unsigned short*)(ws + NE * 6);          // g -> og
    float*         tri = (float*)(ws + NE * 8);                   // [H][J][I]
    unsigned short* Wt = (unsigned short*)(ws + NE * 8 + (size_t)NPOS * 4 * 4);
    unsigned short* xn = Wt + 5 * 16384;                          // bf16 [pos][c]

    prep_kernel<<<5, 256, 0, stream>>>(wq, wk, wv, wg, wo, Wt);
    ln_kernel<<<NPOS / 64, 256, 0, stream>>>(x, ln_g, ln_b, w_tri, xn, tri);
    pgemm_kernel<<<NPOS / 128, 256, 0, stream>>>(xn, Wt, bg, qb, kb, vb, gb);
    attn_kernel<<<I_DIM * H_DIM, 256, 0, stream>>>(qb, kb, vb, gb, tri, mask);
    out_kernel<<<NPOS / 128, 256, 0, stream>>>(gb, Wt + 4 * 16384, bo, out);
}